// Round 1
// baseline (1769.107 us; speedup 1.0000x reference)
//
#include <hip/hip_runtime.h>
#include <math.h>

#define NPTS 32768
#define NP   8192
#define KNN  16
#define CSPLIT 8
#define CHUNK (NP / CSPLIT)   // 1024 candidates per partial block

// ---------------------------------------------------------------------------
// Register-resident sorted (ascending) top-16 insert. Caller guarantees
// d < bd[15]. Strict '<' in the bubble pass keeps equal-distance entries in
// arrival order => lower candidate index wins ties, matching jax.lax.top_k.
// ---------------------------------------------------------------------------
__device__ __forceinline__ void insert16(float (&bd)[16], int (&bi)[16], float d, int id) {
    bd[15] = d; bi[15] = id;
#pragma unroll
    for (int j = 15; j > 0; --j) {
        if (bd[j] < bd[j - 1]) {
            float td = bd[j]; bd[j] = bd[j - 1]; bd[j - 1] = td;
            int   ti = bi[j]; bi[j] = bi[j - 1]; bi[j - 1] = ti;
        }
    }
}

// ---------------------------------------------------------------------------
// K1: partial KNN. grid = (NPTS/256, CSPLIT). Each block: 256 queries
// (one batch), candidate chunk of 1024 staged in LDS as (x,y,z,|p|^2).
// Each thread keeps its top-16 of the chunk in registers, writes sorted
// partial list (dist + global idx) to workspace.
// ---------------------------------------------------------------------------
__global__ __launch_bounds__(256) void knn_partial_kernel(
    const float4* __restrict__ coords, float* __restrict__ pd, int* __restrict__ pi)
{
    __shared__ float4 tile[CHUNK];   // 16 KB

    const int tid = threadIdx.x;
    const int q   = blockIdx.x * 256 + tid;
    const int batch = (blockIdx.x * 256) / NP;          // blocks never straddle batches
    const int cbase = batch * NP + blockIdx.y * CHUNK;  // global candidate base

    for (int c = tid; c < CHUNK; c += 256) {
        float4 f = coords[cbase + c];                   // [bidx, x, y, z]
        float sq = fmaf(f.w, f.w, fmaf(f.z, f.z, f.y * f.y));
        tile[c] = make_float4(f.y, f.z, f.w, sq);
    }

    float4 qf = coords[q];
    const float qx = qf.y, qy = qf.z, qz = qf.w;
    const float sqi = fmaf(qz, qz, fmaf(qy, qy, qx * qx));

    float bd[16]; int bi[16];
#pragma unroll
    for (int j = 0; j < 16; ++j) { bd[j] = INFINITY; bi[j] = 0x7fffffff; }

    __syncthreads();

#pragma unroll 4
    for (int c = 0; c < CHUNK; ++c) {
        float4 t = tile[c];
        float dot = fmaf(qz, t.z, fmaf(qy, t.y, qx * t.x));
        float d = fmaf(-2.0f, dot, sqi) + t.w;          // reference formula ordering
        if (d < bd[15]) insert16(bd, bi, d, cbase + c);
    }

    const size_t base = ((size_t)q * CSPLIT + blockIdx.y) * KNN;
#pragma unroll
    for (int j = 0; j < 16; ++j) { pd[base + j] = bd[j]; pi[base + j] = bi[j]; }
}

// ---------------------------------------------------------------------------
// K2: merge 8 sorted partial lists -> final knn idx; also compute layer-1
// a1 = x(W1t - W1b) + b1 and c1 = x W1b (W1: (32,16) row-major).
// One thread per query. Partial lists are ascending -> early break.
// ---------------------------------------------------------------------------
__global__ __launch_bounds__(256) void knn_merge_ac1_kernel(
    const float* __restrict__ pd, const int* __restrict__ pi,
    const float* __restrict__ feat, const float* __restrict__ W1,
    const float* __restrict__ b1,
    int* __restrict__ knn, float* __restrict__ a1, float* __restrict__ c1)
{
    const int q = blockIdx.x * 256 + threadIdx.x;

    float bd[16]; int bi[16];
#pragma unroll
    for (int j = 0; j < 16; ++j) { bd[j] = INFINITY; bi[j] = 0x7fffffff; }

    for (int s = 0; s < CSPLIT; ++s) {
        const size_t base = ((size_t)q * CSPLIT + s) * KNN;
        for (int j = 0; j < KNN; ++j) {
            float d = pd[base + j];
            if (d >= bd[15]) break;       // sorted ascending -> rest can't enter
            insert16(bd, bi, d, pi[base + j]);
        }
    }
#pragma unroll
    for (int j = 0; j < 16; ++j) knn[q * 16 + j] = bi[j];

    // ---- a1/c1 ----
    float x[16];
    const float4* xf = (const float4*)(feat + (size_t)q * 16);
#pragma unroll
    for (int v = 0; v < 4; ++v) {
        float4 f = xf[v];
        x[4*v] = f.x; x[4*v+1] = f.y; x[4*v+2] = f.z; x[4*v+3] = f.w;
    }
    float av[16], cv[16];
#pragma unroll
    for (int c = 0; c < 16; ++c) { av[c] = b1[c]; cv[c] = 0.0f; }
#pragma unroll
    for (int r = 0; r < 16; ++r) {
        float xr = x[r];
#pragma unroll
        for (int c = 0; c < 16; ++c) {
            float wt = W1[r * 16 + c];          // uniform -> scalar loads
            float wb = W1[(16 + r) * 16 + c];
            av[c] = fmaf(xr, wt - wb, av[c]);
            cv[c] = fmaf(xr, wb, cv[c]);
        }
    }
    float4* a4 = (float4*)(a1 + (size_t)q * 16);
    float4* c4 = (float4*)(c1 + (size_t)q * 16);
#pragma unroll
    for (int v = 0; v < 4; ++v) {
        a4[v] = make_float4(av[4*v], av[4*v+1], av[4*v+2], av[4*v+3]);
        c4[v] = make_float4(cv[4*v], cv[4*v+1], cv[4*v+2], cv[4*v+3]);
    }
}

// ---------------------------------------------------------------------------
// K3/K4/K5: EdgeConv via precomputed a/c:
//   x_out[i] = relu( max_k (a[i] + c[knn[i][k]]) )        (relu commutes w/ max)
// 4 threads per point (CPG = COUT/4 channels each), 64 points/block.
// If !LAST, also computes next layer's a/c from x_out using LDS-staged
// Wm = Wt - Wb and Wb (Wn: (2*COUT, CNXT) row-major).
// ---------------------------------------------------------------------------
template<int COUT, int CNXT, bool LAST>
__global__ __launch_bounds__(256) void edgeconv_kernel(
    const float* __restrict__ a, const float* __restrict__ cf,
    const int* __restrict__ knn,
    const float* __restrict__ Wn, const float* __restrict__ bn,
    float* __restrict__ an, float* __restrict__ cn, float* __restrict__ out)
{
    constexpr int CPG  = COUT / 4;                 // channels per thread (gather/max)
    constexpr int CPGN = LAST ? 4 : CNXT / 4;      // next-layer channels per thread
    constexpr int WSZ  = LAST ? 1 : COUT * CNXT;

    __shared__ float xs[64][COUT + 1];             // +1 pad: kill 16-way bank conflict
    __shared__ __align__(16) float wm[WSZ];
    __shared__ __align__(16) float wb[WSZ];

    const int tid = threadIdx.x;
    const int g = tid & 3, p = tid >> 2;
    const int i = blockIdx.x * 64 + p;

    if constexpr (!LAST) {
        for (int t = tid; t < COUT * CNXT; t += 256) {
            float top = Wn[t], bot = Wn[COUT * CNXT + t];
            wm[t] = top - bot; wb[t] = bot;
        }
    }

    float av[CPG], m[CPG];
    const float4* a4 = (const float4*)(a + (size_t)i * COUT + g * CPG);
#pragma unroll
    for (int v = 0; v < CPG / 4; ++v) {
        float4 f = a4[v];
        av[4*v] = f.x; av[4*v+1] = f.y; av[4*v+2] = f.z; av[4*v+3] = f.w;
    }
#pragma unroll
    for (int c = 0; c < CPG; ++c) m[c] = -INFINITY;

    const int4* kn = (const int4*)(knn + (size_t)i * 16);
#pragma unroll
    for (int kk = 0; kk < 4; ++kk) {
        int4 n4 = kn[kk];
        int js[4] = { n4.x, n4.y, n4.z, n4.w };
#pragma unroll
        for (int u = 0; u < 4; ++u) {
            const float4* c4 = (const float4*)(cf + (size_t)js[u] * COUT + g * CPG);
#pragma unroll
            for (int v = 0; v < CPG / 4; ++v) {
                float4 f = c4[v];
                m[4*v+0] = fmaxf(m[4*v+0], av[4*v+0] + f.x);
                m[4*v+1] = fmaxf(m[4*v+1], av[4*v+1] + f.y);
                m[4*v+2] = fmaxf(m[4*v+2], av[4*v+2] + f.z);
                m[4*v+3] = fmaxf(m[4*v+3], av[4*v+3] + f.w);
            }
        }
    }
    float xv[CPG];
#pragma unroll
    for (int c = 0; c < CPG; ++c) xv[c] = fmaxf(m[c], 0.0f);

    if constexpr (LAST) {
        float4* o4 = (float4*)(out + (size_t)i * COUT + g * CPG);
#pragma unroll
        for (int v = 0; v < CPG / 4; ++v)
            o4[v] = make_float4(xv[4*v], xv[4*v+1], xv[4*v+2], xv[4*v+3]);
    } else {
#pragma unroll
        for (int c = 0; c < CPG; ++c) xs[p][g * CPG + c] = xv[c];
        __syncthreads();   // covers both weight staging and xs

        float aacc[CPGN], cacc[CPGN];
        const float4* bn4 = (const float4*)(bn + g * CPGN);
#pragma unroll
        for (int v = 0; v < CPGN / 4; ++v) {
            float4 f = bn4[v];
            aacc[4*v] = f.x; aacc[4*v+1] = f.y; aacc[4*v+2] = f.z; aacc[4*v+3] = f.w;
        }
#pragma unroll
        for (int c = 0; c < CPGN; ++c) cacc[c] = 0.0f;

#pragma unroll
        for (int r = 0; r < COUT; ++r) {
            float xr = xs[p][r];
            const float4* wm4 = (const float4*)(wm + r * CNXT + g * CPGN);
            const float4* wb4 = (const float4*)(wb + r * CNXT + g * CPGN);
#pragma unroll
            for (int v = 0; v < CPGN / 4; ++v) {
                float4 fm = wm4[v], fb = wb4[v];
                aacc[4*v+0] = fmaf(xr, fm.x, aacc[4*v+0]);
                aacc[4*v+1] = fmaf(xr, fm.y, aacc[4*v+1]);
                aacc[4*v+2] = fmaf(xr, fm.z, aacc[4*v+2]);
                aacc[4*v+3] = fmaf(xr, fm.w, aacc[4*v+3]);
                cacc[4*v+0] = fmaf(xr, fb.x, cacc[4*v+0]);
                cacc[4*v+1] = fmaf(xr, fb.y, cacc[4*v+1]);
                cacc[4*v+2] = fmaf(xr, fb.z, cacc[4*v+2]);
                cacc[4*v+3] = fmaf(xr, fb.w, cacc[4*v+3]);
            }
        }
        float4* an4 = (float4*)(an + (size_t)i * CNXT + g * CPGN);
        float4* cn4 = (float4*)(cn + (size_t)i * CNXT + g * CPGN);
#pragma unroll
        for (int v = 0; v < CPGN / 4; ++v) {
            an4[v] = make_float4(aacc[4*v], aacc[4*v+1], aacc[4*v+2], aacc[4*v+3]);
            cn4[v] = make_float4(cacc[4*v], cacc[4*v+1], cacc[4*v+2], cacc[4*v+3]);
        }
    }
}

// ---------------------------------------------------------------------------
// Workspace layout (bytes):
//   [0,16M)   : pd (partial dists)  -- dead after K2, reused for a2/c2/a3/c3
//   [16M,32M) : pi (partial idxs)
//   [32M,34M) : knn idx (32768 x 16 int)
//   [34M,36M) : a1 ; [36M,38M) : c1
//   reuse:  a2=[0,4M) c2=[4M,8M) a3=[8M,12M) c3=[12M,16M)
// Total required: 38 MB.
// ---------------------------------------------------------------------------
extern "C" void kernel_launch(void* const* d_in, const int* in_sizes, int n_in,
                              void* d_out, int out_size, void* d_ws, size_t ws_size,
                              hipStream_t stream) {
    const float4* coords = (const float4*)d_in[0];
    const float*  feat   = (const float*)d_in[1];
    const float*  W1 = (const float*)d_in[2];
    const float*  b1 = (const float*)d_in[3];
    const float*  W2 = (const float*)d_in[4];
    const float*  b2 = (const float*)d_in[5];
    const float*  W3 = (const float*)d_in[6];
    const float*  b3 = (const float*)d_in[7];
    float* out = (float*)d_out;

    char* ws = (char*)d_ws;
    float* pd  = (float*)(ws);
    int*   pi  = (int*)  (ws + (16u << 20));
    int*   knn = (int*)  (ws + (32u << 20));
    float* a1  = (float*)(ws + (34u << 20));
    float* c1  = (float*)(ws + (36u << 20));
    float* a2  = (float*)(ws + (0u  << 20));
    float* c2  = (float*)(ws + (4u  << 20));
    float* a3  = (float*)(ws + (8u  << 20));
    float* c3  = (float*)(ws + (12u << 20));

    knn_partial_kernel<<<dim3(NPTS / 256, CSPLIT), 256, 0, stream>>>(coords, pd, pi);
    knn_merge_ac1_kernel<<<NPTS / 256, 256, 0, stream>>>(pd, pi, feat, W1, b1, knn, a1, c1);
    edgeconv_kernel<16, 32, false><<<NPTS / 64, 256, 0, stream>>>(a1, c1, knn, W2, b2, a2, c2, nullptr);
    edgeconv_kernel<32, 32, false><<<NPTS / 64, 256, 0, stream>>>(a2, c2, knn, W3, b3, a3, c3, nullptr);
    edgeconv_kernel<32, 4, true><<<NPTS / 64, 256, 0, stream>>>(a3, c3, knn, nullptr, nullptr, nullptr, nullptr, out);
}

// Round 6
// 1584.700 us; speedup vs baseline: 1.1164x; 1.1164x over previous
//
#include <hip/hip_runtime.h>
#include <math.h>

#define NPTS 32768
#define NP   8192
#define KNN  16
#define CSPLIT 8
#define CHUNK (NP / CSPLIT)   // 1024 candidates per partial block
#define QCAP 8                // per-lane LDS candidate queue depth

// ---------------------------------------------------------------------------
// BRANCHLESS sorted (ascending) top-16 insert. Caller guarantees d < bd[15].
// Pure cmp+select => v_cndmask, no divergent branches. Strict '<' keeps
// equal-distance entries in arrival order => lower candidate index wins ties,
// matching jax.lax.top_k.
// ---------------------------------------------------------------------------
__device__ __forceinline__ void insert16(float (&bd)[16], int (&bi)[16], float d, int id) {
    bd[15] = d; bi[15] = id;
#pragma unroll
    for (int j = 15; j > 0; --j) {
        const bool sw = bd[j] < bd[j - 1];
        const float dlo = sw ? bd[j] : bd[j - 1];
        const float dhi = sw ? bd[j - 1] : bd[j];
        const int   ilo = sw ? bi[j] : bi[j - 1];
        const int   ihi = sw ? bi[j - 1] : bi[j];
        bd[j - 1] = dlo; bd[j] = dhi;
        bi[j - 1] = ilo; bi[j] = ihi;
    }
}

// ---------------------------------------------------------------------------
// K1: partial KNN. grid = (NPTS/256, CSPLIT). 256 queries/block (one batch),
// candidate chunk of 1024 staged in LDS as (x,y,z,|p|^2).
//
// Filter-then-insert: the hot loop only does distance + threshold check +
// (rarely-masked) append to a per-lane LDS queue. The expensive sorted insert
// runs only on wave-wide flushes when some lane's queue fills (~10x fewer
// exec-masked insert executions than insert-per-candidate).
// ---------------------------------------------------------------------------
__global__ __launch_bounds__(256) void knn_partial_kernel(
    const float4* __restrict__ coords, float* __restrict__ pd, int* __restrict__ pi)
{
    __shared__ float4 tile[CHUNK];            // 16 KB
    __shared__ float qds[4][QCAP][64];        // per-wave lane queues, 8 KB
    __shared__ int   qis[4][QCAP][64];        // 8 KB

    const int tid  = threadIdx.x;
    const int wave = tid >> 6, lane = tid & 63;
    const int q    = blockIdx.x * 256 + tid;
    const int batch = (blockIdx.x * 256) / NP;          // blocks never straddle batches
    const int cbase = batch * NP + blockIdx.y * CHUNK;  // global candidate base

    for (int c = tid; c < CHUNK; c += 256) {
        float4 f = coords[cbase + c];                   // [bidx, x, y, z]
        float sq = fmaf(f.w, f.w, fmaf(f.z, f.z, f.y * f.y));
        tile[c] = make_float4(f.y, f.z, f.w, sq);
    }

    float4 qf = coords[q];
    const float qx = qf.y, qy = qf.z, qz = qf.w;
    const float sqi = fmaf(qz, qz, fmaf(qy, qy, qx * qx));

    float bd[16]; int bi[16];
#pragma unroll
    for (int j = 0; j < 16; ++j) { bd[j] = INFINITY; bi[j] = 0x7fffffff; }

    int cnt = 0;
    __syncthreads();

    for (int c = 0; c < CHUNK; ++c) {
        float4 t = tile[c];
        float dot = fmaf(qz, t.z, fmaf(qy, t.y, qx * t.x));
        float d = fmaf(-2.0f, dot, sqi) + t.w;          // reference formula ordering
        if (d < bd[15]) {                               // stale-threshold filter (superset, exact)
            qds[wave][cnt][lane] = d;
            qis[wave][cnt][lane] = cbase + c;
            ++cnt;                                      // cnt <= QCAP-1 before append, so no overflow
        }
        if (__any(cnt == QCAP)) {                       // wave-uniform flush
#pragma unroll
            for (int j = 0; j < QCAP; ++j) {
                float fd = qds[wave][j][lane];
                int   fi = qis[wave][j][lane];
                if (j < cnt && fd < bd[15]) insert16(bd, bi, fd, fi);
            }
            cnt = 0;
        }
    }
    // final flush
#pragma unroll
    for (int j = 0; j < QCAP; ++j) {
        float fd = qds[wave][j][lane];
        int   fi = qis[wave][j][lane];
        if (j < cnt && fd < bd[15]) insert16(bd, bi, fd, fi);
    }

    const size_t base = ((size_t)q * CSPLIT + blockIdx.y) * KNN;
#pragma unroll
    for (int j = 0; j < 16; ++j) { pd[base + j] = bd[j]; pi[base + j] = bi[j]; }
}

// ---------------------------------------------------------------------------
// K2: merge 8 sorted partial lists -> final knn idx; also compute layer-1
// a1 = x(W1t - W1b) + b1 and c1 = x W1b (W1: (32,16) row-major).
// One thread per query; 64-thread blocks for grid spread (512 blocks).
// Partial lists are ascending -> early break.
// ---------------------------------------------------------------------------
__global__ __launch_bounds__(64) void knn_merge_ac1_kernel(
    const float* __restrict__ pd, const int* __restrict__ pi,
    const float* __restrict__ feat, const float* __restrict__ W1,
    const float* __restrict__ b1,
    int* __restrict__ knn, float* __restrict__ a1, float* __restrict__ c1)
{
    const int q = blockIdx.x * 64 + threadIdx.x;

    float bd[16]; int bi[16];
#pragma unroll
    for (int j = 0; j < 16; ++j) { bd[j] = INFINITY; bi[j] = 0x7fffffff; }

    for (int s = 0; s < CSPLIT; ++s) {
        const size_t base = ((size_t)q * CSPLIT + s) * KNN;
        for (int j = 0; j < KNN; ++j) {
            float d = pd[base + j];
            if (d >= bd[15]) break;       // sorted ascending -> rest can't enter
            insert16(bd, bi, d, pi[base + j]);
        }
    }
#pragma unroll
    for (int j = 0; j < 16; ++j) knn[q * 16 + j] = bi[j];

    // ---- a1/c1 ----
    float x[16];
    const float4* xf = (const float4*)(feat + (size_t)q * 16);
#pragma unroll
    for (int v = 0; v < 4; ++v) {
        float4 f = xf[v];
        x[4*v] = f.x; x[4*v+1] = f.y; x[4*v+2] = f.z; x[4*v+3] = f.w;
    }
    float av[16], cv[16];
#pragma unroll
    for (int c = 0; c < 16; ++c) { av[c] = b1[c]; cv[c] = 0.0f; }
#pragma unroll
    for (int r = 0; r < 16; ++r) {
        float xr = x[r];
#pragma unroll
        for (int c = 0; c < 16; ++c) {
            float wt = W1[r * 16 + c];          // uniform -> scalar loads
            float wb = W1[(16 + r) * 16 + c];
            av[c] = fmaf(xr, wt - wb, av[c]);
            cv[c] = fmaf(xr, wb, cv[c]);
        }
    }
    float4* a4 = (float4*)(a1 + (size_t)q * 16);
    float4* c4 = (float4*)(c1 + (size_t)q * 16);
#pragma unroll
    for (int v = 0; v < 4; ++v) {
        a4[v] = make_float4(av[4*v], av[4*v+1], av[4*v+2], av[4*v+3]);
        c4[v] = make_float4(cv[4*v], cv[4*v+1], cv[4*v+2], cv[4*v+3]);
    }
}

// ---------------------------------------------------------------------------
// K3/K4/K5: EdgeConv via precomputed a/c:
//   x_out[i] = relu( max_k (a[i] + c[knn[i][k]]) )        (relu commutes w/ max)
// 4 threads per point (CPG = COUT/4 channels each), 64 points/block.
// If !LAST, also computes next layer's a/c from x_out using LDS-staged
// Wm = Wt - Wb and Wb (Wn: (2*COUT, CNXT) row-major).
// ---------------------------------------------------------------------------
template<int COUT, int CNXT, bool LAST>
__global__ __launch_bounds__(256) void edgeconv_kernel(
    const float* __restrict__ a, const float* __restrict__ cf,
    const int* __restrict__ knn,
    const float* __restrict__ Wn, const float* __restrict__ bn,
    float* __restrict__ an, float* __restrict__ cn, float* __restrict__ out)
{
    constexpr int CPG  = COUT / 4;                 // channels per thread (gather/max)
    constexpr int CPGN = LAST ? 4 : CNXT / 4;      // next-layer channels per thread
    constexpr int WSZ  = LAST ? 1 : COUT * CNXT;

    __shared__ float xs[64][COUT + 1];             // +1 pad: kill 16-way bank conflict
    __shared__ __align__(16) float wm[WSZ];
    __shared__ __align__(16) float wb[WSZ];

    const int tid = threadIdx.x;
    const int g = tid & 3, p = tid >> 2;
    const int i = blockIdx.x * 64 + p;

    if constexpr (!LAST) {
        for (int t = tid; t < COUT * CNXT; t += 256) {
            float top = Wn[t], bot = Wn[COUT * CNXT + t];
            wm[t] = top - bot; wb[t] = bot;
        }
    }

    float av[CPG], m[CPG];
    const float4* a4 = (const float4*)(a + (size_t)i * COUT + g * CPG);
#pragma unroll
    for (int v = 0; v < CPG / 4; ++v) {
        float4 f = a4[v];
        av[4*v] = f.x; av[4*v+1] = f.y; av[4*v+2] = f.z; av[4*v+3] = f.w;
    }
#pragma unroll
    for (int c = 0; c < CPG; ++c) m[c] = -INFINITY;

    const int4* kn = (const int4*)(knn + (size_t)i * 16);
#pragma unroll
    for (int kk = 0; kk < 4; ++kk) {
        int4 n4 = kn[kk];
        int js[4] = { n4.x, n4.y, n4.z, n4.w };
#pragma unroll
        for (int u = 0; u < 4; ++u) {
            const float4* c4 = (const float4*)(cf + (size_t)js[u] * COUT + g * CPG);
#pragma unroll
            for (int v = 0; v < CPG / 4; ++v) {
                float4 f = c4[v];
                m[4*v+0] = fmaxf(m[4*v+0], av[4*v+0] + f.x);
                m[4*v+1] = fmaxf(m[4*v+1], av[4*v+1] + f.y);
                m[4*v+2] = fmaxf(m[4*v+2], av[4*v+2] + f.z);
                m[4*v+3] = fmaxf(m[4*v+3], av[4*v+3] + f.w);
            }
        }
    }
    float xv[CPG];
#pragma unroll
    for (int c = 0; c < CPG; ++c) xv[c] = fmaxf(m[c], 0.0f);

    if constexpr (LAST) {
        float4* o4 = (float4*)(out + (size_t)i * COUT + g * CPG);
#pragma unroll
        for (int v = 0; v < CPG / 4; ++v)
            o4[v] = make_float4(xv[4*v], xv[4*v+1], xv[4*v+2], xv[4*v+3]);
    } else {
#pragma unroll
        for (int c = 0; c < CPG; ++c) xs[p][g * CPG + c] = xv[c];
        __syncthreads();   // covers both weight staging and xs

        float aacc[CPGN], cacc[CPGN];
        const float4* bn4 = (const float4*)(bn + g * CPGN);
#pragma unroll
        for (int v = 0; v < CPGN / 4; ++v) {
            float4 f = bn4[v];
            aacc[4*v] = f.x; aacc[4*v+1] = f.y; aacc[4*v+2] = f.z; aacc[4*v+3] = f.w;
        }
#pragma unroll
        for (int c = 0; c < CPGN; ++c) cacc[c] = 0.0f;

#pragma unroll
        for (int r = 0; r < COUT; ++r) {
            float xr = xs[p][r];
            const float4* wm4 = (const float4*)(wm + r * CNXT + g * CPGN);
            const float4* wb4 = (const float4*)(wb + r * CNXT + g * CPGN);
#pragma unroll
            for (int v = 0; v < CPGN / 4; ++v) {
                float4 fm = wm4[v], fb = wb4[v];
                aacc[4*v+0] = fmaf(xr, fm.x, aacc[4*v+0]);
                aacc[4*v+1] = fmaf(xr, fm.y, aacc[4*v+1]);
                aacc[4*v+2] = fmaf(xr, fm.z, aacc[4*v+2]);
                aacc[4*v+3] = fmaf(xr, fm.w, aacc[4*v+3]);
                cacc[4*v+0] = fmaf(xr, fb.x, cacc[4*v+0]);
                cacc[4*v+1] = fmaf(xr, fb.y, cacc[4*v+1]);
                cacc[4*v+2] = fmaf(xr, fb.z, cacc[4*v+2]);
                cacc[4*v+3] = fmaf(xr, fb.w, cacc[4*v+3]);
            }
        }
        float4* an4 = (float4*)(an + (size_t)i * CNXT + g * CPGN);
        float4* cn4 = (float4*)(cn + (size_t)i * CNXT + g * CPGN);
#pragma unroll
        for (int v = 0; v < CPGN / 4; ++v) {
            an4[v] = make_float4(aacc[4*v], aacc[4*v+1], aacc[4*v+2], aacc[4*v+3]);
            cn4[v] = make_float4(cacc[4*v], cacc[4*v+1], cacc[4*v+2], cacc[4*v+3]);
        }
    }
}

// ---------------------------------------------------------------------------
// Workspace layout (bytes):
//   [0,16M)   : pd (partial dists)  -- dead after K2, reused for a2/c2/a3/c3
//   [16M,32M) : pi (partial idxs)
//   [32M,34M) : knn idx (32768 x 16 int)
//   [34M,36M) : a1 ; [36M,38M) : c1
//   reuse:  a2=[0,4M) c2=[4M,8M) a3=[8M,12M) c3=[12M,16M)
// Total required: 38 MB.
// ---------------------------------------------------------------------------
extern "C" void kernel_launch(void* const* d_in, const int* in_sizes, int n_in,
                              void* d_out, int out_size, void* d_ws, size_t ws_size,
                              hipStream_t stream) {
    const float4* coords = (const float4*)d_in[0];
    const float*  feat   = (const float*)d_in[1];
    const float*  W1 = (const float*)d_in[2];
    const float*  b1 = (const float*)d_in[3];
    const float*  W2 = (const float*)d_in[4];
    const float*  b2 = (const float*)d_in[5];
    const float*  W3 = (const float*)d_in[6];
    const float*  b3 = (const float*)d_in[7];
    float* out = (float*)d_out;

    char* ws = (char*)d_ws;
    float* pd  = (float*)(ws);
    int*   pi  = (int*)  (ws + (16u << 20));
    int*   knn = (int*)  (ws + (32u << 20));
    float* a1  = (float*)(ws + (34u << 20));
    float* c1  = (float*)(ws + (36u << 20));
    float* a2  = (float*)(ws + (0u  << 20));
    float* c2  = (float*)(ws + (4u  << 20));
    float* a3  = (float*)(ws + (8u  << 20));
    float* c3  = (float*)(ws + (12u << 20));

    knn_partial_kernel<<<dim3(NPTS / 256, CSPLIT), 256, 0, stream>>>(coords, pd, pi);
    knn_merge_ac1_kernel<<<NPTS / 64, 64, 0, stream>>>(pd, pi, feat, W1, b1, knn, a1, c1);
    edgeconv_kernel<16, 32, false><<<NPTS / 64, 256, 0, stream>>>(a1, c1, knn, W2, b2, a2, c2, nullptr);
    edgeconv_kernel<32, 32, false><<<NPTS / 64, 256, 0, stream>>>(a2, c2, knn, W3, b3, a3, c3, nullptr);
    edgeconv_kernel<32, 4, true><<<NPTS / 64, 256, 0, stream>>>(a3, c3, knn, nullptr, nullptr, nullptr, nullptr, out);
}

// Round 7
// 794.115 us; speedup vs baseline: 2.2278x; 1.9956x over previous
//
#include <hip/hip_runtime.h>
#include <math.h>

#define NPTS 32768
#define NP   8192
#define KNN  16
#define CSPLIT 8
#define CHUNK (NP / CSPLIT)   // 1024 candidates per scan block
#define CAP 192               // survivor capacity per query (P(overflow)~1e-8, exact fallback)

// Shared distance formula — MUST be byte-identical across all phases so the
// float values match exactly (bound / filter / select consistency).
__device__ __forceinline__ float dist2f(float qx, float qy, float qz, float sqi, float4 t) {
    float dot = fmaf(qz, t.z, fmaf(qy, t.y, qx * t.x));
    return fmaf(-2.0f, dot, sqi) + t.w;   // reference formula ordering
}

// ---------------------------------------------------------------------------
// Branchless lexicographic (d, idx) sorted top-16 insert. Strict total order
// (idx distinct) => result independent of insertion order; ties in d resolve
// to lower idx, matching jax.lax.top_k.
// ---------------------------------------------------------------------------
__device__ __forceinline__ void insert_lex(float (&bd)[16], int (&bi)[16], float d, int id) {
    const bool ok = (d < bd[15]) || (d == bd[15] && id < bi[15]);
    bd[15] = ok ? d : bd[15];
    bi[15] = ok ? id : bi[15];
#pragma unroll
    for (int j = 15; j > 0; --j) {
        const bool sw = (bd[j] < bd[j-1]) || (bd[j] == bd[j-1] && bi[j] < bi[j-1]);
        const float dlo = sw ? bd[j] : bd[j-1];
        const float dhi = sw ? bd[j-1] : bd[j];
        const int   ilo = sw ? bi[j] : bi[j-1];
        const int   ihi = sw ? bi[j-1] : bi[j];
        bd[j-1] = dlo; bd[j] = dhi;
        bi[j-1] = ilo; bi[j] = ihi;
    }
}

// ---------------------------------------------------------------------------
// P1: bound. grid (NPTS/256, CSPLIT), 256 thr. Per (query, chunk): track the
// chunk's two smallest distances branchlessly (3 ops), write the 2nd-smallest.
// tau_q = max over chunks of s1 >= d16 exactly: every chunk has >=2 distinct
// candidates with d <= its s1, so >=16 distinct candidates have d <= tau.
// Hot loop: ~9 straight-line VALU/candidate, no branches -> pipelined.
// ---------------------------------------------------------------------------
__global__ __launch_bounds__(256) void knn_bound_kernel(
    const float4* __restrict__ coords, float* __restrict__ pb)
{
    __shared__ float4 tile[CHUNK];   // 16 KB

    const int tid = threadIdx.x;
    const int q   = blockIdx.x * 256 + tid;
    const int batch = (blockIdx.x * 256) / NP;
    const int cbase = batch * NP + blockIdx.y * CHUNK;

    for (int c = tid; c < CHUNK; c += 256) {
        float4 f = coords[cbase + c];                   // [bidx, x, y, z]
        float sq = fmaf(f.w, f.w, fmaf(f.z, f.z, f.y * f.y));
        tile[c] = make_float4(f.y, f.z, f.w, sq);
    }

    float4 qf = coords[q];
    const float qx = qf.y, qy = qf.z, qz = qf.w;
    const float sqi = fmaf(qz, qz, fmaf(qy, qy, qx * qx));

    float s0 = INFINITY, s1 = INFINITY;   // s0 <= s1, chunk's two smallest
    __syncthreads();

#pragma unroll 4
    for (int c = 0; c < CHUNK; ++c) {
        float d = dist2f(qx, qy, qz, sqi, tile[c]);
        float t = fminf(s1, d);
        s1 = fmaxf(s0, t);
        s0 = fminf(s0, t);
    }
    pb[q * CSPLIT + blockIdx.y] = s1;
}

// ---------------------------------------------------------------------------
// P1.5: tau_q = max over 8 chunk bounds; zero the survivor counters.
// ---------------------------------------------------------------------------
__global__ __launch_bounds__(256) void tau_init_kernel(
    const float* __restrict__ pb, float* __restrict__ tau, int* __restrict__ cnt)
{
    const int q = blockIdx.x * 256 + threadIdx.x;
    float t = 0.0f;
#pragma unroll
    for (int s = 0; s < CSPLIT; ++s) t = fmaxf(t, pb[q * CSPLIT + s]);
    tau[q] = t;
    cnt[q] = 0;
}

// ---------------------------------------------------------------------------
// P2: filter. Same decomposition as P1; identical distance floats. Compact
// candidate indices with d <= tau into per-query survivor lists (global
// atomics; ~50-70 survivors/query). pos >= CAP: counted but not stored ->
// P3 detects overflow and falls back to exact brute force.
// ---------------------------------------------------------------------------
__global__ __launch_bounds__(256) void knn_filter_kernel(
    const float4* __restrict__ coords, const float* __restrict__ tau,
    int* __restrict__ cnt, int* __restrict__ surv)
{
    __shared__ float4 tile[CHUNK];

    const int tid = threadIdx.x;
    const int q   = blockIdx.x * 256 + tid;
    const int batch = (blockIdx.x * 256) / NP;
    const int cbase = batch * NP + blockIdx.y * CHUNK;

    for (int c = tid; c < CHUNK; c += 256) {
        float4 f = coords[cbase + c];
        float sq = fmaf(f.w, f.w, fmaf(f.z, f.z, f.y * f.y));
        tile[c] = make_float4(f.y, f.z, f.w, sq);
    }

    float4 qf = coords[q];
    const float qx = qf.y, qy = qf.z, qz = qf.w;
    const float sqi = fmaf(qz, qz, fmaf(qy, qy, qx * qx));
    const float tq = tau[q];

    __syncthreads();

#pragma unroll 4
    for (int c = 0; c < CHUNK; ++c) {
        float d = dist2f(qx, qy, qz, sqi, tile[c]);
        if (d <= tq) {                                   // ~0.8% of lane-steps
            int pos = atomicAdd(&cnt[q], 1);
            if (pos < CAP) surv[(size_t)q * CAP + pos] = cbase + c;
        }
    }
}

// ---------------------------------------------------------------------------
// P3: exact top-16 among survivors (lex (d,idx) order -> deterministic,
// jax tie-break), then layer-1 a1 = x(W1t-W1b)+b1, c1 = x W1b.
// One thread per query, 128-thread blocks (256 blocks).
// ---------------------------------------------------------------------------
__global__ __launch_bounds__(128) void knn_select_ac1_kernel(
    const float4* __restrict__ coords, const int* __restrict__ cnt,
    const int* __restrict__ surv,
    const float* __restrict__ feat, const float* __restrict__ W1,
    const float* __restrict__ b1,
    int* __restrict__ knn, float* __restrict__ a1, float* __restrict__ c1)
{
    const int q = blockIdx.x * 128 + threadIdx.x;

    float4 qf = coords[q];
    const float qx = qf.y, qy = qf.z, qz = qf.w;
    const float sqi = fmaf(qz, qz, fmaf(qy, qy, qx * qx));

    float bd[16]; int bi[16];
#pragma unroll
    for (int j = 0; j < 16; ++j) { bd[j] = INFINITY; bi[j] = 0x7fffffff; }

    const int n = cnt[q];
    if (n <= CAP) {
        for (int j = 0; j < n; ++j) {
            int id = surv[(size_t)q * CAP + j];
            float4 f = coords[id];
            float sq = fmaf(f.w, f.w, fmaf(f.z, f.z, f.y * f.y));
            float d = dist2f(qx, qy, qz, sqi, make_float4(f.y, f.z, f.w, sq));
            insert_lex(bd, bi, d, id);
        }
    } else {                                   // exact fallback (P ~ 1e-8)
        const int b0 = (q / NP) * NP;
        for (int c = 0; c < NP; ++c) {
            int id = b0 + c;
            float4 f = coords[id];
            float sq = fmaf(f.w, f.w, fmaf(f.z, f.z, f.y * f.y));
            float d = dist2f(qx, qy, qz, sqi, make_float4(f.y, f.z, f.w, sq));
            insert_lex(bd, bi, d, id);
        }
    }
#pragma unroll
    for (int j = 0; j < 16; ++j) knn[q * 16 + j] = bi[j];

    // ---- a1/c1 ----
    float x[16];
    const float4* xf = (const float4*)(feat + (size_t)q * 16);
#pragma unroll
    for (int v = 0; v < 4; ++v) {
        float4 f = xf[v];
        x[4*v] = f.x; x[4*v+1] = f.y; x[4*v+2] = f.z; x[4*v+3] = f.w;
    }
    float av[16], cv[16];
#pragma unroll
    for (int c = 0; c < 16; ++c) { av[c] = b1[c]; cv[c] = 0.0f; }
#pragma unroll
    for (int r = 0; r < 16; ++r) {
        float xr = x[r];
#pragma unroll
        for (int c = 0; c < 16; ++c) {
            float wt = W1[r * 16 + c];
            float wb = W1[(16 + r) * 16 + c];
            av[c] = fmaf(xr, wt - wb, av[c]);
            cv[c] = fmaf(xr, wb, cv[c]);
        }
    }
    float4* a4 = (float4*)(a1 + (size_t)q * 16);
    float4* c4 = (float4*)(c1 + (size_t)q * 16);
#pragma unroll
    for (int v = 0; v < 4; ++v) {
        a4[v] = make_float4(av[4*v], av[4*v+1], av[4*v+2], av[4*v+3]);
        c4[v] = make_float4(cv[4*v], cv[4*v+1], cv[4*v+2], cv[4*v+3]);
    }
}

// ---------------------------------------------------------------------------
// EdgeConv (unchanged from the passing round-0 version):
//   x_out[i] = relu( max_k (a[i] + c[knn[i][k]]) )
// ---------------------------------------------------------------------------
template<int COUT, int CNXT, bool LAST>
__global__ __launch_bounds__(256) void edgeconv_kernel(
    const float* __restrict__ a, const float* __restrict__ cf,
    const int* __restrict__ knn,
    const float* __restrict__ Wn, const float* __restrict__ bn,
    float* __restrict__ an, float* __restrict__ cn, float* __restrict__ out)
{
    constexpr int CPG  = COUT / 4;
    constexpr int CPGN = LAST ? 4 : CNXT / 4;
    constexpr int WSZ  = LAST ? 1 : COUT * CNXT;

    __shared__ float xs[64][COUT + 1];
    __shared__ __align__(16) float wm[WSZ];
    __shared__ __align__(16) float wb[WSZ];

    const int tid = threadIdx.x;
    const int g = tid & 3, p = tid >> 2;
    const int i = blockIdx.x * 64 + p;

    if constexpr (!LAST) {
        for (int t = tid; t < COUT * CNXT; t += 256) {
            float top = Wn[t], bot = Wn[COUT * CNXT + t];
            wm[t] = top - bot; wb[t] = bot;
        }
    }

    float av[CPG], m[CPG];
    const float4* a4 = (const float4*)(a + (size_t)i * COUT + g * CPG);
#pragma unroll
    for (int v = 0; v < CPG / 4; ++v) {
        float4 f = a4[v];
        av[4*v] = f.x; av[4*v+1] = f.y; av[4*v+2] = f.z; av[4*v+3] = f.w;
    }
#pragma unroll
    for (int c = 0; c < CPG; ++c) m[c] = -INFINITY;

    const int4* kn = (const int4*)(knn + (size_t)i * 16);
#pragma unroll
    for (int kk = 0; kk < 4; ++kk) {
        int4 n4 = kn[kk];
        int js[4] = { n4.x, n4.y, n4.z, n4.w };
#pragma unroll
        for (int u = 0; u < 4; ++u) {
            const float4* c4 = (const float4*)(cf + (size_t)js[u] * COUT + g * CPG);
#pragma unroll
            for (int v = 0; v < CPG / 4; ++v) {
                float4 f = c4[v];
                m[4*v+0] = fmaxf(m[4*v+0], av[4*v+0] + f.x);
                m[4*v+1] = fmaxf(m[4*v+1], av[4*v+1] + f.y);
                m[4*v+2] = fmaxf(m[4*v+2], av[4*v+2] + f.z);
                m[4*v+3] = fmaxf(m[4*v+3], av[4*v+3] + f.w);
            }
        }
    }
    float xv[CPG];
#pragma unroll
    for (int c = 0; c < CPG; ++c) xv[c] = fmaxf(m[c], 0.0f);

    if constexpr (LAST) {
        float4* o4 = (float4*)(out + (size_t)i * COUT + g * CPG);
#pragma unroll
        for (int v = 0; v < CPG / 4; ++v)
            o4[v] = make_float4(xv[4*v], xv[4*v+1], xv[4*v+2], xv[4*v+3]);
    } else {
#pragma unroll
        for (int c = 0; c < CPG; ++c) xs[p][g * CPG + c] = xv[c];
        __syncthreads();

        float aacc[CPGN], cacc[CPGN];
        const float4* bn4 = (const float4*)(bn + g * CPGN);
#pragma unroll
        for (int v = 0; v < CPGN / 4; ++v) {
            float4 f = bn4[v];
            aacc[4*v] = f.x; aacc[4*v+1] = f.y; aacc[4*v+2] = f.z; aacc[4*v+3] = f.w;
        }
#pragma unroll
        for (int c = 0; c < CPGN; ++c) cacc[c] = 0.0f;

#pragma unroll
        for (int r = 0; r < COUT; ++r) {
            float xr = xs[p][r];
            const float4* wm4 = (const float4*)(wm + r * CNXT + g * CPGN);
            const float4* wb4 = (const float4*)(wb + r * CNXT + g * CPGN);
#pragma unroll
            for (int v = 0; v < CPGN / 4; ++v) {
                float4 fm = wm4[v], fb = wb4[v];
                aacc[4*v+0] = fmaf(xr, fm.x, aacc[4*v+0]);
                aacc[4*v+1] = fmaf(xr, fm.y, aacc[4*v+1]);
                aacc[4*v+2] = fmaf(xr, fm.z, aacc[4*v+2]);
                aacc[4*v+3] = fmaf(xr, fm.w, aacc[4*v+3]);
                cacc[4*v+0] = fmaf(xr, fb.x, cacc[4*v+0]);
                cacc[4*v+1] = fmaf(xr, fb.y, cacc[4*v+1]);
                cacc[4*v+2] = fmaf(xr, fb.z, cacc[4*v+2]);
                cacc[4*v+3] = fmaf(xr, fb.w, cacc[4*v+3]);
            }
        }
        float4* an4 = (float4*)(an + (size_t)i * CNXT + g * CPGN);
        float4* cn4 = (float4*)(cn + (size_t)i * CNXT + g * CPGN);
#pragma unroll
        for (int v = 0; v < CPGN / 4; ++v) {
            an4[v] = make_float4(aacc[4*v], aacc[4*v+1], aacc[4*v+2], aacc[4*v+3]);
            cn4[v] = make_float4(cacc[4*v], cacc[4*v+1], cacc[4*v+2], cacc[4*v+3]);
        }
    }
}

// ---------------------------------------------------------------------------
// Workspace layout (bytes), total 33 MB (<= proven 38 MB budget):
//   [0,24M)        : surv (32768 x 192 int)   -- dead after P3, reused
//   [24M,25M)      : pb  (32768 x 8 float)
//   [26M,+128K)    : tau ; [26M+128K,+128K) : cnt
//   [27M,29M)      : knn (32768 x 16 int)
//   [29M,31M)      : a1 ; [31M,33M) : c1
//   reuse: a2=[0,4M) c2=[4,8M) a3=[8,12M) c3=[12,16M)
// ---------------------------------------------------------------------------
extern "C" void kernel_launch(void* const* d_in, const int* in_sizes, int n_in,
                              void* d_out, int out_size, void* d_ws, size_t ws_size,
                              hipStream_t stream) {
    const float4* coords = (const float4*)d_in[0];
    const float*  feat   = (const float*)d_in[1];
    const float*  W1 = (const float*)d_in[2];
    const float*  b1 = (const float*)d_in[3];
    const float*  W2 = (const float*)d_in[4];
    const float*  b2 = (const float*)d_in[5];
    const float*  W3 = (const float*)d_in[6];
    const float*  b3 = (const float*)d_in[7];
    float* out = (float*)d_out;

    char* ws = (char*)d_ws;
    int*   surv = (int*)  (ws);
    float* pb   = (float*)(ws + (24u << 20));
    float* tau  = (float*)(ws + (26u << 20));
    int*   cnt  = (int*)  (ws + (26u << 20) + (128u << 10));
    int*   knn  = (int*)  (ws + (27u << 20));
    float* a1   = (float*)(ws + (29u << 20));
    float* c1   = (float*)(ws + (31u << 20));
    float* a2   = (float*)(ws + (0u  << 20));
    float* c2   = (float*)(ws + (4u  << 20));
    float* a3   = (float*)(ws + (8u  << 20));
    float* c3   = (float*)(ws + (12u << 20));

    knn_bound_kernel<<<dim3(NPTS / 256, CSPLIT), 256, 0, stream>>>(coords, pb);
    tau_init_kernel<<<NPTS / 256, 256, 0, stream>>>(pb, tau, cnt);
    knn_filter_kernel<<<dim3(NPTS / 256, CSPLIT), 256, 0, stream>>>(coords, tau, cnt, surv);
    knn_select_ac1_kernel<<<NPTS / 128, 128, 0, stream>>>(coords, cnt, surv, feat, W1, b1, knn, a1, c1);
    edgeconv_kernel<16, 32, false><<<NPTS / 64, 256, 0, stream>>>(a1, c1, knn, W2, b2, a2, c2, nullptr);
    edgeconv_kernel<32, 32, false><<<NPTS / 64, 256, 0, stream>>>(a2, c2, knn, W3, b3, a3, c3, nullptr);
    edgeconv_kernel<32, 4, true><<<NPTS / 64, 256, 0, stream>>>(a3, c3, knn, nullptr, nullptr, nullptr, nullptr, out);
}

// Round 8
// 387.874 us; speedup vs baseline: 4.5610x; 2.0474x over previous
//
#include <hip/hip_runtime.h>
#include <math.h>

#define NPTS 32768
#define NP   8192
#define KNN  16
#define CSPLIT 8
#define CHUNK (NP / CSPLIT)   // 1024 candidates per scan block
#define CAP 192               // survivor capacity per query (P(overflow)~1e-8, exact fallback)

// Shared distance formula — byte-identical across all phases so float values
// match exactly (bound / filter / select consistency).
__device__ __forceinline__ float dist2f(float qx, float qy, float qz, float sqi, float4 t) {
    float dot = fmaf(qz, t.z, fmaf(qy, t.y, qx * t.x));
    return fmaf(-2.0f, dot, sqi) + t.w;   // reference formula ordering
}

// Branchless lexicographic (d, idx) sorted top-16 insert (fallback path only).
__device__ __forceinline__ void insert_lex(float (&bd)[16], int (&bi)[16], float d, int id) {
    const bool ok = (d < bd[15]) || (d == bd[15] && id < bi[15]);
    bd[15] = ok ? d : bd[15];
    bi[15] = ok ? id : bi[15];
#pragma unroll
    for (int j = 15; j > 0; --j) {
        const bool sw = (bd[j] < bd[j-1]) || (bd[j] == bd[j-1] && bi[j] < bi[j-1]);
        const float dlo = sw ? bd[j] : bd[j-1];
        const float dhi = sw ? bd[j-1] : bd[j];
        const int   ilo = sw ? bi[j] : bi[j-1];
        const int   ihi = sw ? bi[j-1] : bi[j];
        bd[j-1] = dlo; bd[j] = dhi;
        bi[j-1] = ilo; bi[j] = ihi;
    }
}

// ---------------------------------------------------------------------------
// P1: bound. Per (query, chunk) keep the chunk's two smallest distances
// branchlessly; write the 2nd-smallest. tau_q = max over chunks >= d16 exact.
// ---------------------------------------------------------------------------
__global__ __launch_bounds__(256) void knn_bound_kernel(
    const float4* __restrict__ coords, float* __restrict__ pb)
{
    __shared__ float4 tile[CHUNK];   // 16 KB

    const int tid = threadIdx.x;
    const int q   = blockIdx.x * 256 + tid;
    const int batch = (blockIdx.x * 256) / NP;
    const int cbase = batch * NP + blockIdx.y * CHUNK;

    for (int c = tid; c < CHUNK; c += 256) {
        float4 f = coords[cbase + c];                   // [bidx, x, y, z]
        float sq = fmaf(f.w, f.w, fmaf(f.z, f.z, f.y * f.y));
        tile[c] = make_float4(f.y, f.z, f.w, sq);
    }

    float4 qf = coords[q];
    const float qx = qf.y, qy = qf.z, qz = qf.w;
    const float sqi = fmaf(qz, qz, fmaf(qy, qy, qx * qx));

    float s0 = INFINITY, s1 = INFINITY;   // s0 <= s1
    __syncthreads();

#pragma unroll 4
    for (int c = 0; c < CHUNK; ++c) {
        float d = dist2f(qx, qy, qz, sqi, tile[c]);
        float t = fminf(s1, d);
        s1 = fmaxf(s0, t);
        s0 = fminf(s0, t);
    }
    pb[q * CSPLIT + blockIdx.y] = s1;
}

// ---------------------------------------------------------------------------
// P1.5: tau_q = max over 8 chunk bounds; zero survivor counters.
// ---------------------------------------------------------------------------
__global__ __launch_bounds__(256) void tau_init_kernel(
    const float* __restrict__ pb, float* __restrict__ tau, int* __restrict__ cnt)
{
    const int q = blockIdx.x * 256 + threadIdx.x;
    float t = 0.0f;
#pragma unroll
    for (int s = 0; s < CSPLIT; ++s) t = fmaxf(t, pb[q * CSPLIT + s]);
    tau[q] = t;
    cnt[q] = 0;
}

// ---------------------------------------------------------------------------
// P2: filter. Identical distance floats; compact indices with d <= tau into
// per-query survivor lists (global atomics; ~40-70 survivors/query).
// ---------------------------------------------------------------------------
__global__ __launch_bounds__(256) void knn_filter_kernel(
    const float4* __restrict__ coords, const float* __restrict__ tau,
    int* __restrict__ cnt, int* __restrict__ surv)
{
    __shared__ float4 tile[CHUNK];

    const int tid = threadIdx.x;
    const int q   = blockIdx.x * 256 + tid;
    const int batch = (blockIdx.x * 256) / NP;
    const int cbase = batch * NP + blockIdx.y * CHUNK;

    for (int c = tid; c < CHUNK; c += 256) {
        float4 f = coords[cbase + c];
        float sq = fmaf(f.w, f.w, fmaf(f.z, f.z, f.y * f.y));
        tile[c] = make_float4(f.y, f.z, f.w, sq);
    }

    float4 qf = coords[q];
    const float qx = qf.y, qy = qf.z, qz = qf.w;
    const float sqi = fmaf(qz, qz, fmaf(qy, qy, qx * qx));
    const float tq = tau[q];

    __syncthreads();

#pragma unroll 4
    for (int c = 0; c < CHUNK; ++c) {
        float d = dist2f(qx, qy, qz, sqi, tile[c]);
        if (d <= tq) {
            int pos = atomicAdd(&cnt[q], 1);
            if (pos < CAP) surv[(size_t)q * CAP + pos] = cbase + c;
        }
    }
}

// ---------------------------------------------------------------------------
// P3: WAVE-PARALLEL exact top-16 + layer-1 a1/c1.
// One wave (64-thread block) per query. Lane j owns survivors j, j+64, j+128:
// coalesced surv read, 64 parallel coords gathers (L2-resident 512KB table).
// Rank = all-pairs lex-(d,id) count against LDS-staged survivors: no serial
// dependency chain, wave-uniform loops. rank<16 scatters id to LDS slot rank
// (bijective: strict total order). Then 16 lanes compute a1/c1 channels.
// Single-wave block => all __syncthreads sit in wave-uniform control flow.
// ---------------------------------------------------------------------------
__global__ __launch_bounds__(64) void knn_select_ac1_kernel(
    const float4* __restrict__ coords, const int* __restrict__ cnt,
    const int* __restrict__ surv,
    const float* __restrict__ feat, const float* __restrict__ W1,
    const float* __restrict__ b1,
    int* __restrict__ knn, float* __restrict__ a1, float* __restrict__ c1)
{
    __shared__ float sd[CAP];
    __shared__ int   si[CAP];
    __shared__ int   outi[16];
    __shared__ float sx[16];

    const int lane = threadIdx.x;
    const int q    = blockIdx.x;

    float4 qf = coords[q];
    const float qx = qf.y, qy = qf.z, qz = qf.w;
    const float sqi = fmaf(qz, qz, fmaf(qy, qy, qx * qx));

    const int n = cnt[q];                 // wave-uniform (>=16 by construction)

    if (n <= CAP) {
        float dv[3]; int iv[3];
#pragma unroll
        for (int b = 0; b < 3; ++b) {
            const int j = b * 64 + lane;
            float d = INFINITY; int id = 0x7fffffff;
            if (j < n) {
                id = surv[(size_t)q * CAP + j];
                float4 f = coords[id];
                float sq = fmaf(f.w, f.w, fmaf(f.z, f.z, f.y * f.y));
                d = dist2f(qx, qy, qz, sqi, make_float4(f.y, f.z, f.w, sq));
            }
            dv[b] = d; iv[b] = id;
            if (j < CAP) { sd[j] = d; si[j] = id; }
        }
        __syncthreads();

        int r0 = 0, r1 = 0, r2 = 0;
        if (n <= 64) {                    // common case (~99.9%): 1 block live
            for (int k = 0; k < n; ++k) {
                float dk = sd[k]; int ik = si[k];
                r0 += ((dk < dv[0]) || (dk == dv[0] && ik < iv[0])) ? 1 : 0;
            }
        } else {
            for (int k = 0; k < n; ++k) {
                float dk = sd[k]; int ik = si[k];
                r0 += ((dk < dv[0]) || (dk == dv[0] && ik < iv[0])) ? 1 : 0;
                r1 += ((dk < dv[1]) || (dk == dv[1] && ik < iv[1])) ? 1 : 0;
                r2 += ((dk < dv[2]) || (dk == dv[2] && ik < iv[2])) ? 1 : 0;
            }
        }
        if (lane       < n && r0 < 16) outi[r0] = iv[0];
        if (lane + 64  < n && r1 < 16) outi[r1] = iv[1];
        if (lane + 128 < n && r2 < 16) outi[r2] = iv[2];
        __syncthreads();
    } else {                              // exact fallback (P ~ 1e-8)
        if (lane == 0) {
            float bd[16]; int bi[16];
#pragma unroll
            for (int j = 0; j < 16; ++j) { bd[j] = INFINITY; bi[j] = 0x7fffffff; }
            const int b0 = (q / NP) * NP;
            for (int c = 0; c < NP; ++c) {
                int id = b0 + c;
                float4 f = coords[id];
                float sq = fmaf(f.w, f.w, fmaf(f.z, f.z, f.y * f.y));
                float d = dist2f(qx, qy, qz, sqi, make_float4(f.y, f.z, f.w, sq));
                insert_lex(bd, bi, d, id);
            }
#pragma unroll
            for (int j = 0; j < 16; ++j) outi[j] = bi[j];
        }
        __syncthreads();
    }

    if (lane < 16) {
        knn[q * 16 + lane] = outi[lane];
        sx[lane] = feat[(size_t)q * 16 + lane];
    }
    __syncthreads();

    // ---- a1/c1: lane c (<16) computes channel c ----
    if (lane < 16) {
        float av = b1[lane], cv = 0.0f;
#pragma unroll
        for (int r = 0; r < 16; ++r) {
            float xr = sx[r];
            float wt = W1[r * 16 + lane];
            float wb = W1[(16 + r) * 16 + lane];
            av = fmaf(xr, wt - wb, av);
            cv = fmaf(xr, wb, cv);
        }
        a1[(size_t)q * 16 + lane] = av;
        c1[(size_t)q * 16 + lane] = cv;
    }
}

// ---------------------------------------------------------------------------
// EdgeConv (unchanged, passing since round 0):
//   x_out[i] = relu( max_k (a[i] + c[knn[i][k]]) )
// ---------------------------------------------------------------------------
template<int COUT, int CNXT, bool LAST>
__global__ __launch_bounds__(256) void edgeconv_kernel(
    const float* __restrict__ a, const float* __restrict__ cf,
    const int* __restrict__ knn,
    const float* __restrict__ Wn, const float* __restrict__ bn,
    float* __restrict__ an, float* __restrict__ cn, float* __restrict__ out)
{
    constexpr int CPG  = COUT / 4;
    constexpr int CPGN = LAST ? 4 : CNXT / 4;
    constexpr int WSZ  = LAST ? 1 : COUT * CNXT;

    __shared__ float xs[64][COUT + 1];
    __shared__ __align__(16) float wm[WSZ];
    __shared__ __align__(16) float wb[WSZ];

    const int tid = threadIdx.x;
    const int g = tid & 3, p = tid >> 2;
    const int i = blockIdx.x * 64 + p;

    if constexpr (!LAST) {
        for (int t = tid; t < COUT * CNXT; t += 256) {
            float top = Wn[t], bot = Wn[COUT * CNXT + t];
            wm[t] = top - bot; wb[t] = bot;
        }
    }

    float av[CPG], m[CPG];
    const float4* a4 = (const float4*)(a + (size_t)i * COUT + g * CPG);
#pragma unroll
    for (int v = 0; v < CPG / 4; ++v) {
        float4 f = a4[v];
        av[4*v] = f.x; av[4*v+1] = f.y; av[4*v+2] = f.z; av[4*v+3] = f.w;
    }
#pragma unroll
    for (int c = 0; c < CPG; ++c) m[c] = -INFINITY;

    const int4* kn = (const int4*)(knn + (size_t)i * 16);
#pragma unroll
    for (int kk = 0; kk < 4; ++kk) {
        int4 n4 = kn[kk];
        int js[4] = { n4.x, n4.y, n4.z, n4.w };
#pragma unroll
        for (int u = 0; u < 4; ++u) {
            const float4* c4 = (const float4*)(cf + (size_t)js[u] * COUT + g * CPG);
#pragma unroll
            for (int v = 0; v < CPG / 4; ++v) {
                float4 f = c4[v];
                m[4*v+0] = fmaxf(m[4*v+0], av[4*v+0] + f.x);
                m[4*v+1] = fmaxf(m[4*v+1], av[4*v+1] + f.y);
                m[4*v+2] = fmaxf(m[4*v+2], av[4*v+2] + f.z);
                m[4*v+3] = fmaxf(m[4*v+3], av[4*v+3] + f.w);
            }
        }
    }
    float xv[CPG];
#pragma unroll
    for (int c = 0; c < CPG; ++c) xv[c] = fmaxf(m[c], 0.0f);

    if constexpr (LAST) {
        float4* o4 = (float4*)(out + (size_t)i * COUT + g * CPG);
#pragma unroll
        for (int v = 0; v < CPG / 4; ++v)
            o4[v] = make_float4(xv[4*v], xv[4*v+1], xv[4*v+2], xv[4*v+3]);
    } else {
#pragma unroll
        for (int c = 0; c < CPG; ++c) xs[p][g * CPG + c] = xv[c];
        __syncthreads();

        float aacc[CPGN], cacc[CPGN];
        const float4* bn4 = (const float4*)(bn + g * CPGN);
#pragma unroll
        for (int v = 0; v < CPGN / 4; ++v) {
            float4 f = bn4[v];
            aacc[4*v] = f.x; aacc[4*v+1] = f.y; aacc[4*v+2] = f.z; aacc[4*v+3] = f.w;
        }
#pragma unroll
        for (int c = 0; c < CPGN; ++c) cacc[c] = 0.0f;

#pragma unroll
        for (int r = 0; r < COUT; ++r) {
            float xr = xs[p][r];
            const float4* wm4 = (const float4*)(wm + r * CNXT + g * CPGN);
            const float4* wb4 = (const float4*)(wb + r * CNXT + g * CPGN);
#pragma unroll
            for (int v = 0; v < CPGN / 4; ++v) {
                float4 fm = wm4[v], fb = wb4[v];
                aacc[4*v+0] = fmaf(xr, fm.x, aacc[4*v+0]);
                aacc[4*v+1] = fmaf(xr, fm.y, aacc[4*v+1]);
                aacc[4*v+2] = fmaf(xr, fm.z, aacc[4*v+2]);
                aacc[4*v+3] = fmaf(xr, fm.w, aacc[4*v+3]);
                cacc[4*v+0] = fmaf(xr, fb.x, cacc[4*v+0]);
                cacc[4*v+1] = fmaf(xr, fb.y, cacc[4*v+1]);
                cacc[4*v+2] = fmaf(xr, fb.z, cacc[4*v+2]);
                cacc[4*v+3] = fmaf(xr, fb.w, cacc[4*v+3]);
            }
        }
        float4* an4 = (float4*)(an + (size_t)i * CNXT + g * CPGN);
        float4* cn4 = (float4*)(cn + (size_t)i * CNXT + g * CPGN);
#pragma unroll
        for (int v = 0; v < CPGN / 4; ++v) {
            an4[v] = make_float4(aacc[4*v], aacc[4*v+1], aacc[4*v+2], aacc[4*v+3]);
            cn4[v] = make_float4(cacc[4*v], cacc[4*v+1], cacc[4*v+2], cacc[4*v+3]);
        }
    }
}

// ---------------------------------------------------------------------------
// Workspace layout (bytes), total 33 MB:
//   [0,24M)        : surv (32768 x 192 int)   -- dead after P3, reused
//   [24M,25M)      : pb  (32768 x 8 float)
//   [26M,+128K)    : tau ; [26M+128K,+128K) : cnt
//   [27M,29M)      : knn (32768 x 16 int)
//   [29M,31M)      : a1 ; [31M,33M) : c1
//   reuse: a2=[0,4M) c2=[4,8M) a3=[8,12M) c3=[12,16M)
// ---------------------------------------------------------------------------
extern "C" void kernel_launch(void* const* d_in, const int* in_sizes, int n_in,
                              void* d_out, int out_size, void* d_ws, size_t ws_size,
                              hipStream_t stream) {
    const float4* coords = (const float4*)d_in[0];
    const float*  feat   = (const float*)d_in[1];
    const float*  W1 = (const float*)d_in[2];
    const float*  b1 = (const float*)d_in[3];
    const float*  W2 = (const float*)d_in[4];
    const float*  b2 = (const float*)d_in[5];
    const float*  W3 = (const float*)d_in[6];
    const float*  b3 = (const float*)d_in[7];
    float* out = (float*)d_out;

    char* ws = (char*)d_ws;
    int*   surv = (int*)  (ws);
    float* pb   = (float*)(ws + (24u << 20));
    float* tau  = (float*)(ws + (26u << 20));
    int*   cnt  = (int*)  (ws + (26u << 20) + (128u << 10));
    int*   knn  = (int*)  (ws + (27u << 20));
    float* a1   = (float*)(ws + (29u << 20));
    float* c1   = (float*)(ws + (31u << 20));
    float* a2   = (float*)(ws + (0u  << 20));
    float* c2   = (float*)(ws + (4u  << 20));
    float* a3   = (float*)(ws + (8u  << 20));
    float* c3   = (float*)(ws + (12u << 20));

    knn_bound_kernel<<<dim3(NPTS / 256, CSPLIT), 256, 0, stream>>>(coords, pb);
    tau_init_kernel<<<NPTS / 256, 256, 0, stream>>>(pb, tau, cnt);
    knn_filter_kernel<<<dim3(NPTS / 256, CSPLIT), 256, 0, stream>>>(coords, tau, cnt, surv);
    knn_select_ac1_kernel<<<NPTS, 64, 0, stream>>>(coords, cnt, surv, feat, W1, b1, knn, a1, c1);
    edgeconv_kernel<16, 32, false><<<NPTS / 64, 256, 0, stream>>>(a1, c1, knn, W2, b2, a2, c2, nullptr);
    edgeconv_kernel<32, 32, false><<<NPTS / 64, 256, 0, stream>>>(a2, c2, knn, W3, b3, a3, c3, nullptr);
    edgeconv_kernel<32, 4, true><<<NPTS / 64, 256, 0, stream>>>(a3, c3, knn, nullptr, nullptr, nullptr, nullptr, out);
}

// Round 10
// 369.149 us; speedup vs baseline: 4.7924x; 1.0507x over previous
//
#include <hip/hip_runtime.h>
#include <math.h>

#define NPTS 32768
#define NP   8192
#define KNN  16
#define CSPLIT 8
#define CHUNK (NP / CSPLIT)   // 1024 candidates per scan block
#define SEGCAP 24             // survivor slots per (query, chunk) segment
#define NSLOT (CSPLIT * SEGCAP)   // 192 slots per query

// Shared distance formula — byte-identical across all phases so float values
// match exactly (bound / filter / select consistency).
__device__ __forceinline__ float dist2f(float qx, float qy, float qz, float sqi, float4 t) {
    float dot = fmaf(qz, t.z, fmaf(qy, t.y, qx * t.x));
    return fmaf(-2.0f, dot, sqi) + t.w;   // reference formula ordering
}

// Branchless lexicographic (d, idx) sorted top-16 insert (fallback path only).
__device__ __forceinline__ void insert_lex(float (&bd)[16], int (&bi)[16], float d, int id) {
    const bool ok = (d < bd[15]) || (d == bd[15] && id < bi[15]);
    bd[15] = ok ? d : bd[15];
    bi[15] = ok ? id : bi[15];
#pragma unroll
    for (int j = 15; j > 0; --j) {
        const bool sw = (bd[j] < bd[j-1]) || (bd[j] == bd[j-1] && bi[j] < bi[j-1]);
        const float dlo = sw ? bd[j] : bd[j-1];
        const float dhi = sw ? bd[j-1] : bd[j];
        const int   ilo = sw ? bi[j] : bi[j-1];
        const int   ihi = sw ? bi[j-1] : bi[j];
        bd[j-1] = dlo; bd[j] = dhi;
        bi[j-1] = ilo; bi[j] = ihi;
    }
}

// ---------------------------------------------------------------------------
// P1: bound. Per (query, chunk) keep the chunk's two smallest distances
// branchlessly; write the 2nd-smallest. tau_q = max over chunks >= d16 exact
// (every chunk contributes >=2 distinct candidates with d <= its s1).
// ---------------------------------------------------------------------------
__global__ __launch_bounds__(256) void knn_bound_kernel(
    const float4* __restrict__ coords, float* __restrict__ pb)
{
    __shared__ float4 tile[CHUNK];   // 16 KB

    const int tid = threadIdx.x;
    const int q   = blockIdx.x * 256 + tid;
    const int batch = (blockIdx.x * 256) / NP;
    const int cbase = batch * NP + blockIdx.y * CHUNK;

    for (int c = tid; c < CHUNK; c += 256) {
        float4 f = coords[cbase + c];                   // [bidx, x, y, z]
        float sq = fmaf(f.w, f.w, fmaf(f.z, f.z, f.y * f.y));
        tile[c] = make_float4(f.y, f.z, f.w, sq);
    }

    float4 qf = coords[q];
    const float qx = qf.y, qy = qf.z, qz = qf.w;
    const float sqi = fmaf(qz, qz, fmaf(qy, qy, qx * qx));

    float s0 = INFINITY, s1 = INFINITY;   // s0 <= s1
    __syncthreads();

#pragma unroll 4
    for (int c = 0; c < CHUNK; ++c) {
        float d = dist2f(qx, qy, qz, sqi, tile[c]);
        float t = fminf(s1, d);
        s1 = fmaxf(s0, t);
        s0 = fminf(s0, t);
    }
    pb[q * CSPLIT + blockIdx.y] = s1;
}

// ---------------------------------------------------------------------------
// P1.5: tau_q = max over 8 chunk bounds.
// ---------------------------------------------------------------------------
__global__ __launch_bounds__(256) void tau_init_kernel(
    const float* __restrict__ pb, float* __restrict__ tau)
{
    const int q = blockIdx.x * 256 + threadIdx.x;
    float t = 0.0f;
#pragma unroll
    for (int s = 0; s < CSPLIT; ++s) t = fmaxf(t, pb[q * CSPLIT + s]);
    tau[q] = t;
}

// ---------------------------------------------------------------------------
// P2: filter — ATOMIC-FREE. Each (query, chunk) is scanned by exactly one
// thread, so the survivor position within the per-(q,chunk) segment is a
// thread-local counter. Accept path = fire-and-forget store (no value-
// returning atomic round-trip — that was 223us @ 24% VALUBusy in round 8).
// Segment count written once at the end (raw, for overflow detection).
// ---------------------------------------------------------------------------
__global__ __launch_bounds__(256) void knn_filter_kernel(
    const float4* __restrict__ coords, const float* __restrict__ tau,
    int* __restrict__ pc, int* __restrict__ surv)
{
    __shared__ float4 tile[CHUNK];

    const int tid = threadIdx.x;
    const int q   = blockIdx.x * 256 + tid;
    const int batch = (blockIdx.x * 256) / NP;
    const int cbase = batch * NP + blockIdx.y * CHUNK;

    for (int c = tid; c < CHUNK; c += 256) {
        float4 f = coords[cbase + c];
        float sq = fmaf(f.w, f.w, fmaf(f.z, f.z, f.y * f.y));
        tile[c] = make_float4(f.y, f.z, f.w, sq);
    }

    float4 qf = coords[q];
    const float qx = qf.y, qy = qf.z, qz = qf.w;
    const float sqi = fmaf(qz, qz, fmaf(qy, qy, qx * qx));
    const float tq = tau[q];

    const size_t sbase = (size_t)q * NSLOT + blockIdx.y * SEGCAP;
    int cnt = 0;
    __syncthreads();

#pragma unroll 4
    for (int c = 0; c < CHUNK; ++c) {
        float d = dist2f(qx, qy, qz, sqi, tile[c]);
        if (d <= tq) {                         // ~0.67% of lane-steps
            if (cnt < SEGCAP) surv[sbase + cnt] = cbase + c;
            ++cnt;
        }
    }
    pc[q * CSPLIT + blockIdx.y] = cnt;
}

// ---------------------------------------------------------------------------
// P3: WAVE-PARALLEL exact top-16 + layer-1 a1/c1.
// One wave per query. Slot j in [0,192): seg=j/24, off=j%24, valid iff
// off < pc[seg]. Invalid slots get (INF, INT_MAX): their rank >= n >= 16,
// so they never enter the top-16. Rank = all-pairs lex-(d,id) count over the
// LDS-staged slots (strict total order -> bijective ranks, exact jax
// tie-break, independent of store order). Single-wave block => __syncthreads
// in wave-uniform control flow only.
// ---------------------------------------------------------------------------
__global__ __launch_bounds__(64) void knn_select_ac1_kernel(
    const float4* __restrict__ coords, const int* __restrict__ pc,
    const int* __restrict__ surv,
    const float* __restrict__ feat, const float* __restrict__ W1,
    const float* __restrict__ b1,
    int* __restrict__ knn, float* __restrict__ a1, float* __restrict__ c1)
{
    __shared__ float sd[NSLOT];
    __shared__ int   si[NSLOT];
    __shared__ int   spc[CSPLIT];
    __shared__ int   outi[16];
    __shared__ float sx[16];

    const int lane = threadIdx.x;
    const int q    = blockIdx.x;

    float4 qf = coords[q];
    const float qx = qf.y, qy = qf.z, qz = qf.w;
    const float sqi = fmaf(qz, qz, fmaf(qy, qy, qx * qx));

    if (lane < CSPLIT) spc[lane] = pc[q * CSPLIT + lane];
    __syncthreads();

    bool over = false;
#pragma unroll
    for (int s = 0; s < CSPLIT; ++s) over |= (spc[s] > SEGCAP);   // wave-uniform

    if (!over) {
        float dv[3]; int iv[3];
#pragma unroll
        for (int b = 0; b < 3; ++b) {
            const int j = b * 64 + lane;          // j < 192 always
            const int seg = j / SEGCAP;
            const int off = j - seg * SEGCAP;
            float d = INFINITY; int id = 0x7fffffff;
            if (off < spc[seg]) {
                id = surv[(size_t)q * NSLOT + j];
                float4 f = coords[id];
                float sq = fmaf(f.w, f.w, fmaf(f.z, f.z, f.y * f.y));
                d = dist2f(qx, qy, qz, sqi, make_float4(f.y, f.z, f.w, sq));
            }
            dv[b] = d; iv[b] = id;
            sd[j] = d; si[j] = id;
        }
        __syncthreads();

        int r0 = 0, r1 = 0, r2 = 0;
        for (int k = 0; k < NSLOT; ++k) {         // LDS broadcast reads
            float dk = sd[k]; int ik = si[k];
            r0 += ((dk < dv[0]) || (dk == dv[0] && ik < iv[0])) ? 1 : 0;
            r1 += ((dk < dv[1]) || (dk == dv[1] && ik < iv[1])) ? 1 : 0;
            r2 += ((dk < dv[2]) || (dk == dv[2] && ik < iv[2])) ? 1 : 0;
        }
        if (r0 < 16) outi[r0] = iv[0];            // invalid slots have rank>=16
        if (r1 < 16) outi[r1] = iv[1];
        if (r2 < 16) outi[r2] = iv[2];
        __syncthreads();
    } else {                                      // exact fallback (P ~ 1e-7)
        if (lane == 0) {
            float bd[16]; int bi[16];
#pragma unroll
            for (int j = 0; j < 16; ++j) { bd[j] = INFINITY; bi[j] = 0x7fffffff; }
            const int b0 = (q / NP) * NP;
            for (int c = 0; c < NP; ++c) {
                int id = b0 + c;
                float4 f = coords[id];
                float sq = fmaf(f.w, f.w, fmaf(f.z, f.z, f.y * f.y));
                float d = dist2f(qx, qy, qz, sqi, make_float4(f.y, f.z, f.w, sq));
                insert_lex(bd, bi, d, id);
            }
#pragma unroll
            for (int j = 0; j < 16; ++j) outi[j] = bi[j];
        }
        __syncthreads();
    }

    if (lane < 16) {
        knn[q * 16 + lane] = outi[lane];
        sx[lane] = feat[(size_t)q * 16 + lane];
    }
    __syncthreads();

    // ---- a1/c1: lane c (<16) computes channel c ----
    if (lane < 16) {
        float av = b1[lane], cv = 0.0f;
#pragma unroll
        for (int r = 0; r < 16; ++r) {
            float xr = sx[r];
            float wt = W1[r * 16 + lane];
            float wb = W1[(16 + r) * 16 + lane];
            av = fmaf(xr, wt - wb, av);
            cv = fmaf(xr, wb, cv);
        }
        a1[(size_t)q * 16 + lane] = av;
        c1[(size_t)q * 16 + lane] = cv;
    }
}

// ---------------------------------------------------------------------------
// EdgeConv (unchanged, passing since round 0):
//   x_out[i] = relu( max_k (a[i] + c[knn[i][k]]) )
// ---------------------------------------------------------------------------
template<int COUT, int CNXT, bool LAST>
__global__ __launch_bounds__(256) void edgeconv_kernel(
    const float* __restrict__ a, const float* __restrict__ cf,
    const int* __restrict__ knn,
    const float* __restrict__ Wn, const float* __restrict__ bn,
    float* __restrict__ an, float* __restrict__ cn, float* __restrict__ out)
{
    constexpr int CPG  = COUT / 4;
    constexpr int CPGN = LAST ? 4 : CNXT / 4;
    constexpr int WSZ  = LAST ? 1 : COUT * CNXT;

    __shared__ float xs[64][COUT + 1];
    __shared__ __align__(16) float wm[WSZ];
    __shared__ __align__(16) float wb[WSZ];

    const int tid = threadIdx.x;
    const int g = tid & 3, p = tid >> 2;
    const int i = blockIdx.x * 64 + p;

    if constexpr (!LAST) {
        for (int t = tid; t < COUT * CNXT; t += 256) {
            float top = Wn[t], bot = Wn[COUT * CNXT + t];
            wm[t] = top - bot; wb[t] = bot;
        }
    }

    float av[CPG], m[CPG];
    const float4* a4 = (const float4*)(a + (size_t)i * COUT + g * CPG);
#pragma unroll
    for (int v = 0; v < CPG / 4; ++v) {
        float4 f = a4[v];
        av[4*v] = f.x; av[4*v+1] = f.y; av[4*v+2] = f.z; av[4*v+3] = f.w;
    }
#pragma unroll
    for (int c = 0; c < CPG; ++c) m[c] = -INFINITY;

    const int4* kn = (const int4*)(knn + (size_t)i * 16);
#pragma unroll
    for (int kk = 0; kk < 4; ++kk) {
        int4 n4 = kn[kk];
        int js[4] = { n4.x, n4.y, n4.z, n4.w };
#pragma unroll
        for (int u = 0; u < 4; ++u) {
            const float4* c4 = (const float4*)(cf + (size_t)js[u] * COUT + g * CPG);
#pragma unroll
            for (int v = 0; v < CPG / 4; ++v) {
                float4 f = c4[v];
                m[4*v+0] = fmaxf(m[4*v+0], av[4*v+0] + f.x);
                m[4*v+1] = fmaxf(m[4*v+1], av[4*v+1] + f.y);
                m[4*v+2] = fmaxf(m[4*v+2], av[4*v+2] + f.z);
                m[4*v+3] = fmaxf(m[4*v+3], av[4*v+3] + f.w);
            }
        }
    }
    float xv[CPG];
#pragma unroll
    for (int c = 0; c < CPG; ++c) xv[c] = fmaxf(m[c], 0.0f);

    if constexpr (LAST) {
        float4* o4 = (float4*)(out + (size_t)i * COUT + g * CPG);
#pragma unroll
        for (int v = 0; v < CPG / 4; ++v)
            o4[v] = make_float4(xv[4*v], xv[4*v+1], xv[4*v+2], xv[4*v+3]);
    } else {
#pragma unroll
        for (int c = 0; c < CPG; ++c) xs[p][g * CPG + c] = xv[c];
        __syncthreads();

        float aacc[CPGN], cacc[CPGN];
        const float4* bn4 = (const float4*)(bn + g * CPGN);
#pragma unroll
        for (int v = 0; v < CPGN / 4; ++v) {
            float4 f = bn4[v];
            aacc[4*v] = f.x; aacc[4*v+1] = f.y; aacc[4*v+2] = f.z; aacc[4*v+3] = f.w;
        }
#pragma unroll
        for (int c = 0; c < CPGN; ++c) cacc[c] = 0.0f;

#pragma unroll
        for (int r = 0; r < COUT; ++r) {
            float xr = xs[p][r];
            const float4* wm4 = (const float4*)(wm + r * CNXT + g * CPGN);
            const float4* wb4 = (const float4*)(wb + r * CNXT + g * CPGN);
#pragma unroll
            for (int v = 0; v < CPGN / 4; ++v) {
                float4 fm = wm4[v], fb = wb4[v];
                aacc[4*v+0] = fmaf(xr, fm.x, aacc[4*v+0]);
                aacc[4*v+1] = fmaf(xr, fm.y, aacc[4*v+1]);
                aacc[4*v+2] = fmaf(xr, fm.z, aacc[4*v+2]);
                aacc[4*v+3] = fmaf(xr, fm.w, aacc[4*v+3]);
                cacc[4*v+0] = fmaf(xr, fb.x, cacc[4*v+0]);
                cacc[4*v+1] = fmaf(xr, fb.y, cacc[4*v+1]);
                cacc[4*v+2] = fmaf(xr, fb.z, cacc[4*v+2]);
                cacc[4*v+3] = fmaf(xr, fb.w, cacc[4*v+3]);
            }
        }
        float4* an4 = (float4*)(an + (size_t)i * CNXT + g * CPGN);
        float4* cn4 = (float4*)(cn + (size_t)i * CNXT + g * CPGN);
#pragma unroll
        for (int v = 0; v < CPGN / 4; ++v) {
            an4[v] = make_float4(aacc[4*v], aacc[4*v+1], aacc[4*v+2], aacc[4*v+3]);
            cn4[v] = make_float4(cacc[4*v], cacc[4*v+1], cacc[4*v+2], cacc[4*v+3]);
        }
    }
}

// ---------------------------------------------------------------------------
// Workspace layout (bytes), total 33 MB:
//   [0,24M)   : surv (32768 x 192 int, segmented 8x24)  -- dead after P3
//   [24M,25M) : pb  (32768 x 8 float)
//   [25M,+128K): tau
//   [26M,27M) : pc  (32768 x 8 int)
//   [27M,29M) : knn (32768 x 16 int)
//   [29M,31M) : a1 ; [31M,33M) : c1
//   reuse: a2=[0,4M) c2=[4,8M) a3=[8,12M) c3=[12,16M)
// ---------------------------------------------------------------------------
extern "C" void kernel_launch(void* const* d_in, const int* in_sizes, int n_in,
                              void* d_out, int out_size, void* d_ws, size_t ws_size,
                              hipStream_t stream) {
    const float4* coords = (const float4*)d_in[0];
    const float*  feat   = (const float*)d_in[1];
    const float*  W1 = (const float*)d_in[2];
    const float*  b1 = (const float*)d_in[3];
    const float*  W2 = (const float*)d_in[4];
    const float*  b2 = (const float*)d_in[5];
    const float*  W3 = (const float*)d_in[6];
    const float*  b3 = (const float*)d_in[7];
    float* out = (float*)d_out;

    char* ws = (char*)d_ws;
    int*   surv = (int*)  (ws);
    float* pb   = (float*)(ws + (24u << 20));
    float* tau  = (float*)(ws + (25u << 20));
    int*   pc   = (int*)  (ws + (26u << 20));
    int*   knn  = (int*)  (ws + (27u << 20));
    float* a1   = (float*)(ws + (29u << 20));
    float* c1   = (float*)(ws + (31u << 20));
    float* a2   = (float*)(ws + (0u  << 20));
    float* c2   = (float*)(ws + (4u  << 20));
    float* a3   = (float*)(ws + (8u  << 20));
    float* c3   = (float*)(ws + (12u << 20));

    knn_bound_kernel<<<dim3(NPTS / 256, CSPLIT), 256, 0, stream>>>(coords, pb);
    tau_init_kernel<<<NPTS / 256, 256, 0, stream>>>(pb, tau);
    knn_filter_kernel<<<dim3(NPTS / 256, CSPLIT), 256, 0, stream>>>(coords, tau, pc, surv);
    knn_select_ac1_kernel<<<NPTS, 64, 0, stream>>>(coords, pc, surv, feat, W1, b1, knn, a1, c1);
    edgeconv_kernel<16, 32, false><<<NPTS / 64, 256, 0, stream>>>(a1, c1, knn, W2, b2, a2, c2, nullptr);
    edgeconv_kernel<32, 32, false><<<NPTS / 64, 256, 0, stream>>>(a2, c2, knn, W3, b3, a3, c3, nullptr);
    edgeconv_kernel<32, 4, true><<<NPTS / 64, 256, 0, stream>>>(a3, c3, knn, nullptr, nullptr, nullptr, nullptr, out);
}

// Round 11
// 308.029 us; speedup vs baseline: 5.7433x; 1.1984x over previous
//
#include <hip/hip_runtime.h>
#include <math.h>

#define NPTS 32768
#define NP   8192
#define KNN  16
#define CSPLIT 8
#define CHUNK (NP / CSPLIT)       // 1024 candidates per scan block
#define SEGCAP 24                 // survivor slots per (query, chunk) segment
#define NSLOT (CSPLIT * SEGCAP)   // 192 slots per query
#define QPT 2                     // queries per thread in scan kernels
#define QBLK (256 * QPT)          // queries per scan block = 512

// Shared distance formula — byte-identical across all phases so float values
// match exactly (bound / filter / select consistency).
__device__ __forceinline__ float dist2f(float qx, float qy, float qz, float sqi, float4 t) {
    float dot = fmaf(qz, t.z, fmaf(qy, t.y, qx * t.x));
    return fmaf(-2.0f, dot, sqi) + t.w;   // reference formula ordering
}

// Branchless lexicographic (d, idx) sorted top-16 insert (fallback path only).
__device__ __forceinline__ void insert_lex(float (&bd)[16], int (&bi)[16], float d, int id) {
    const bool ok = (d < bd[15]) || (d == bd[15] && id < bi[15]);
    bd[15] = ok ? d : bd[15];
    bi[15] = ok ? id : bi[15];
#pragma unroll
    for (int j = 15; j > 0; --j) {
        const bool sw = (bd[j] < bd[j-1]) || (bd[j] == bd[j-1] && bi[j] < bi[j-1]);
        const float dlo = sw ? bd[j] : bd[j-1];
        const float dhi = sw ? bd[j-1] : bd[j];
        const int   ilo = sw ? bi[j] : bi[j-1];
        const int   ihi = sw ? bi[j-1] : bi[j];
        bd[j-1] = dlo; bd[j] = dhi;
        bi[j-1] = ilo; bi[j] = ihi;
    }
}

// ---------------------------------------------------------------------------
// P1: bound, QPT=2. Each thread scans the chunk for TWO queries (q0 = qb+tid,
// q1 = qb+256+tid, both coalesced), amortizing the per-candidate LDS read
// over 2 distance computations. Per (query, chunk): branchless 2-smallest;
// write the 2nd-smallest. tau_q = max over chunks >= d16 exact.
// ---------------------------------------------------------------------------
__global__ __launch_bounds__(256) void knn_bound_kernel(
    const float4* __restrict__ coords, float* __restrict__ pb)
{
    __shared__ float4 tile[CHUNK];   // 16 KB

    const int tid = threadIdx.x;
    const int qb  = blockIdx.x * QBLK;          // 512-query window, never straddles batch
    const int batch = qb / NP;
    const int cbase = batch * NP + blockIdx.y * CHUNK;

    for (int c = tid; c < CHUNK; c += 256) {
        float4 f = coords[cbase + c];                   // [bidx, x, y, z]
        float sq = fmaf(f.w, f.w, fmaf(f.z, f.z, f.y * f.y));
        tile[c] = make_float4(f.y, f.z, f.w, sq);
    }

    const int q0 = qb + tid, q1 = qb + 256 + tid;
    float4 qf0 = coords[q0];
    float4 qf1 = coords[q1];
    const float qx0 = qf0.y, qy0 = qf0.z, qz0 = qf0.w;
    const float qx1 = qf1.y, qy1 = qf1.z, qz1 = qf1.w;
    const float sqi0 = fmaf(qz0, qz0, fmaf(qy0, qy0, qx0 * qx0));
    const float sqi1 = fmaf(qz1, qz1, fmaf(qy1, qy1, qx1 * qx1));

    float a0 = INFINITY, a1 = INFINITY;   // q0: smallest, 2nd-smallest
    float b0 = INFINITY, b1 = INFINITY;   // q1
    __syncthreads();

#pragma unroll 4
    for (int c = 0; c < CHUNK; ++c) {
        float4 t = tile[c];
        float d0 = dist2f(qx0, qy0, qz0, sqi0, t);
        float d1 = dist2f(qx1, qy1, qz1, sqi1, t);
        float t0 = fminf(a1, d0);
        a1 = fmaxf(a0, t0);
        a0 = fminf(a0, t0);
        float t1 = fminf(b1, d1);
        b1 = fmaxf(b0, t1);
        b0 = fminf(b0, t1);
    }
    pb[q0 * CSPLIT + blockIdx.y] = a1;
    pb[q1 * CSPLIT + blockIdx.y] = b1;
}

// ---------------------------------------------------------------------------
// P1.5: tau_q = max over 8 chunk bounds.
// ---------------------------------------------------------------------------
__global__ __launch_bounds__(256) void tau_init_kernel(
    const float* __restrict__ pb, float* __restrict__ tau)
{
    const int q = blockIdx.x * 256 + threadIdx.x;
    float t = 0.0f;
#pragma unroll
    for (int s = 0; s < CSPLIT; ++s) t = fmaxf(t, pb[q * CSPLIT + s]);
    tau[q] = t;
}

// ---------------------------------------------------------------------------
// P2: filter, QPT=2, ATOMIC-FREE. Each (query, chunk) still scanned by
// exactly one thread => thread-local segment counters, fire-and-forget
// stores. Segment counts written raw at the end (overflow detection).
// ---------------------------------------------------------------------------
__global__ __launch_bounds__(256) void knn_filter_kernel(
    const float4* __restrict__ coords, const float* __restrict__ tau,
    int* __restrict__ pc, int* __restrict__ surv)
{
    __shared__ float4 tile[CHUNK];

    const int tid = threadIdx.x;
    const int qb  = blockIdx.x * QBLK;
    const int batch = qb / NP;
    const int cbase = batch * NP + blockIdx.y * CHUNK;

    for (int c = tid; c < CHUNK; c += 256) {
        float4 f = coords[cbase + c];
        float sq = fmaf(f.w, f.w, fmaf(f.z, f.z, f.y * f.y));
        tile[c] = make_float4(f.y, f.z, f.w, sq);
    }

    const int q0 = qb + tid, q1 = qb + 256 + tid;
    float4 qf0 = coords[q0];
    float4 qf1 = coords[q1];
    const float qx0 = qf0.y, qy0 = qf0.z, qz0 = qf0.w;
    const float qx1 = qf1.y, qy1 = qf1.z, qz1 = qf1.w;
    const float sqi0 = fmaf(qz0, qz0, fmaf(qy0, qy0, qx0 * qx0));
    const float sqi1 = fmaf(qz1, qz1, fmaf(qy1, qy1, qx1 * qx1));
    const float tq0 = tau[q0], tq1 = tau[q1];

    const size_t sb0 = (size_t)q0 * NSLOT + blockIdx.y * SEGCAP;
    const size_t sb1 = (size_t)q1 * NSLOT + blockIdx.y * SEGCAP;
    int cnt0 = 0, cnt1 = 0;
    __syncthreads();

#pragma unroll 4
    for (int c = 0; c < CHUNK; ++c) {
        float4 t = tile[c];
        float d0 = dist2f(qx0, qy0, qz0, sqi0, t);
        float d1 = dist2f(qx1, qy1, qz1, sqi1, t);
        if (d0 <= tq0) {
            if (cnt0 < SEGCAP) surv[sb0 + cnt0] = cbase + c;
            ++cnt0;
        }
        if (d1 <= tq1) {
            if (cnt1 < SEGCAP) surv[sb1 + cnt1] = cbase + c;
            ++cnt1;
        }
    }
    pc[q0 * CSPLIT + blockIdx.y] = cnt0;
    pc[q1 * CSPLIT + blockIdx.y] = cnt1;
}

// ---------------------------------------------------------------------------
// P3: WAVE-PARALLEL exact top-16 + layer-1 a1/c1 — COMPACTED rank.
// Survivors are written into LDS at compacted positions off[seg]+o (prefix
// offsets of segment counts, wave-uniform registers). The rank loop then
// runs only k < n (~56 avg) instead of all 192 slots, and the common case
// n <= 64 (86%) ranks a single owned slot. Ranks of valid entries are
// unchanged vs round 10 (pads were lex-greater => contributed 0). Strict
// lex (d,id) total order -> bijective ranks, exact jax tie-break.
// Single-wave block => __syncthreads only in wave-uniform control flow.
// ---------------------------------------------------------------------------
__global__ __launch_bounds__(64) void knn_select_ac1_kernel(
    const float4* __restrict__ coords, const int* __restrict__ pc,
    const int* __restrict__ surv,
    const float* __restrict__ feat, const float* __restrict__ W1,
    const float* __restrict__ b1,
    int* __restrict__ knn, float* __restrict__ a1, float* __restrict__ c1)
{
    __shared__ float sd[NSLOT];
    __shared__ int   si[NSLOT];
    __shared__ int   spc[CSPLIT];
    __shared__ int   outi[16];
    __shared__ float sx[16];

    const int lane = threadIdx.x;
    const int q    = blockIdx.x;

    float4 qf = coords[q];
    const float qx = qf.y, qy = qf.z, qz = qf.w;
    const float sqi = fmaf(qz, qz, fmaf(qy, qy, qx * qx));

    if (lane < CSPLIT) spc[lane] = pc[q * CSPLIT + lane];
    __syncthreads();

    // Wave-uniform: prefix offsets + overflow flag + total n.
    int off[CSPLIT];
    bool over = false;
    int acc = 0;
#pragma unroll
    for (int s = 0; s < CSPLIT; ++s) {
        int c = spc[s];
        over |= (c > SEGCAP);
        off[s] = acc;
        acc += c;
    }
    const int n = acc;                        // >= 16 by construction (2/segment)

    if (!over) {
        // Compacted stage: slot j -> LDS position off[seg]+o (injective).
#pragma unroll
        for (int b = 0; b < 3; ++b) {
            const int j = b * 64 + lane;      // j < 192
            const int seg = j / SEGCAP;
            const int o   = j - seg * SEGCAP;
            if (o < spc[seg]) {
                int id = surv[(size_t)q * NSLOT + j];
                float4 f = coords[id];
                float sq = fmaf(f.w, f.w, fmaf(f.z, f.z, f.y * f.y));
                float d = dist2f(qx, qy, qz, sqi, make_float4(f.y, f.z, f.w, sq));
                const int pos = off[seg] + o;
                sd[pos] = d; si[pos] = id;
            }
        }
        __syncthreads();

        if (n <= 64) {                        // fast path (~86% of queries)
            float dm = INFINITY; int im = 0x7fffffff;
            if (lane < n) { dm = sd[lane]; im = si[lane]; }
            int r = 0;
            for (int k = 0; k < n; ++k) {     // LDS broadcast reads
                float dk = sd[k]; int ik = si[k];
                r += ((dk < dm) || (dk == dm && ik < im)) ? 1 : 0;
            }
            if (lane < n && r < 16) outi[r] = im;
        } else {
            float dm[3]; int im[3];
#pragma unroll
            for (int b = 0; b < 3; ++b) {
                const int m = b * 64 + lane;
                dm[b] = (m < n) ? sd[m] : INFINITY;
                im[b] = (m < n) ? si[m] : 0x7fffffff;
            }
            int r0 = 0, r1 = 0, r2 = 0;
            for (int k = 0; k < n; ++k) {
                float dk = sd[k]; int ik = si[k];
                r0 += ((dk < dm[0]) || (dk == dm[0] && ik < im[0])) ? 1 : 0;
                r1 += ((dk < dm[1]) || (dk == dm[1] && ik < im[1])) ? 1 : 0;
                r2 += ((dk < dm[2]) || (dk == dm[2] && ik < im[2])) ? 1 : 0;
            }
            if (lane       < n && r0 < 16) outi[r0] = im[0];
            if (lane + 64  < n && r1 < 16) outi[r1] = im[1];
            if (lane + 128 < n && r2 < 16) outi[r2] = im[2];
        }
        __syncthreads();
    } else {                                  // exact fallback (P ~ 1e-7)
        if (lane == 0) {
            float bd[16]; int bi[16];
#pragma unroll
            for (int j = 0; j < 16; ++j) { bd[j] = INFINITY; bi[j] = 0x7fffffff; }
            const int b0 = (q / NP) * NP;
            for (int c = 0; c < NP; ++c) {
                int id = b0 + c;
                float4 f = coords[id];
                float sq = fmaf(f.w, f.w, fmaf(f.z, f.z, f.y * f.y));
                float d = dist2f(qx, qy, qz, sqi, make_float4(f.y, f.z, f.w, sq));
                insert_lex(bd, bi, d, id);
            }
#pragma unroll
            for (int j = 0; j < 16; ++j) outi[j] = bi[j];
        }
        __syncthreads();
    }

    if (lane < 16) {
        knn[q * 16 + lane] = outi[lane];
        sx[lane] = feat[(size_t)q * 16 + lane];
    }
    __syncthreads();

    // ---- a1/c1: lane c (<16) computes channel c ----
    if (lane < 16) {
        float av = b1[lane], cv = 0.0f;
#pragma unroll
        for (int r = 0; r < 16; ++r) {
            float xr = sx[r];
            float wt = W1[r * 16 + lane];
            float wb = W1[(16 + r) * 16 + lane];
            av = fmaf(xr, wt - wb, av);
            cv = fmaf(xr, wb, cv);
        }
        a1[(size_t)q * 16 + lane] = av;
        c1[(size_t)q * 16 + lane] = cv;
    }
}

// ---------------------------------------------------------------------------
// EdgeConv (unchanged, passing since round 0):
//   x_out[i] = relu( max_k (a[i] + c[knn[i][k]]) )
// ---------------------------------------------------------------------------
template<int COUT, int CNXT, bool LAST>
__global__ __launch_bounds__(256) void edgeconv_kernel(
    const float* __restrict__ a, const float* __restrict__ cf,
    const int* __restrict__ knn,
    const float* __restrict__ Wn, const float* __restrict__ bn,
    float* __restrict__ an, float* __restrict__ cn, float* __restrict__ out)
{
    constexpr int CPG  = COUT / 4;
    constexpr int CPGN = LAST ? 4 : CNXT / 4;
    constexpr int WSZ  = LAST ? 1 : COUT * CNXT;

    __shared__ float xs[64][COUT + 1];
    __shared__ __align__(16) float wm[WSZ];
    __shared__ __align__(16) float wb[WSZ];

    const int tid = threadIdx.x;
    const int g = tid & 3, p = tid >> 2;
    const int i = blockIdx.x * 64 + p;

    if constexpr (!LAST) {
        for (int t = tid; t < COUT * CNXT; t += 256) {
            float top = Wn[t], bot = Wn[COUT * CNXT + t];
            wm[t] = top - bot; wb[t] = bot;
        }
    }

    float av[CPG], m[CPG];
    const float4* a4 = (const float4*)(a + (size_t)i * COUT + g * CPG);
#pragma unroll
    for (int v = 0; v < CPG / 4; ++v) {
        float4 f = a4[v];
        av[4*v] = f.x; av[4*v+1] = f.y; av[4*v+2] = f.z; av[4*v+3] = f.w;
    }
#pragma unroll
    for (int c = 0; c < CPG; ++c) m[c] = -INFINITY;

    const int4* kn = (const int4*)(knn + (size_t)i * 16);
#pragma unroll
    for (int kk = 0; kk < 4; ++kk) {
        int4 n4 = kn[kk];
        int js[4] = { n4.x, n4.y, n4.z, n4.w };
#pragma unroll
        for (int u = 0; u < 4; ++u) {
            const float4* c4 = (const float4*)(cf + (size_t)js[u] * COUT + g * CPG);
#pragma unroll
            for (int v = 0; v < CPG / 4; ++v) {
                float4 f = c4[v];
                m[4*v+0] = fmaxf(m[4*v+0], av[4*v+0] + f.x);
                m[4*v+1] = fmaxf(m[4*v+1], av[4*v+1] + f.y);
                m[4*v+2] = fmaxf(m[4*v+2], av[4*v+2] + f.z);
                m[4*v+3] = fmaxf(m[4*v+3], av[4*v+3] + f.w);
            }
        }
    }
    float xv[CPG];
#pragma unroll
    for (int c = 0; c < CPG; ++c) xv[c] = fmaxf(m[c], 0.0f);

    if constexpr (LAST) {
        float4* o4 = (float4*)(out + (size_t)i * COUT + g * CPG);
#pragma unroll
        for (int v = 0; v < CPG / 4; ++v)
            o4[v] = make_float4(xv[4*v], xv[4*v+1], xv[4*v+2], xv[4*v+3]);
    } else {
#pragma unroll
        for (int c = 0; c < CPG; ++c) xs[p][g * CPG + c] = xv[c];
        __syncthreads();

        float aacc[CPGN], cacc[CPGN];
        const float4* bn4 = (const float4*)(bn + g * CPGN);
#pragma unroll
        for (int v = 0; v < CPGN / 4; ++v) {
            float4 f = bn4[v];
            aacc[4*v] = f.x; aacc[4*v+1] = f.y; aacc[4*v+2] = f.z; aacc[4*v+3] = f.w;
        }
#pragma unroll
        for (int c = 0; c < CPGN; ++c) cacc[c] = 0.0f;

#pragma unroll
        for (int r = 0; r < COUT; ++r) {
            float xr = xs[p][r];
            const float4* wm4 = (const float4*)(wm + r * CNXT + g * CPGN);
            const float4* wb4 = (const float4*)(wb + r * CNXT + g * CPGN);
#pragma unroll
            for (int v = 0; v < CPGN / 4; ++v) {
                float4 fm = wm4[v], fb = wb4[v];
                aacc[4*v+0] = fmaf(xr, fm.x, aacc[4*v+0]);
                aacc[4*v+1] = fmaf(xr, fm.y, aacc[4*v+1]);
                aacc[4*v+2] = fmaf(xr, fm.z, aacc[4*v+2]);
                aacc[4*v+3] = fmaf(xr, fm.w, aacc[4*v+3]);
                cacc[4*v+0] = fmaf(xr, fb.x, cacc[4*v+0]);
                cacc[4*v+1] = fmaf(xr, fb.y, cacc[4*v+1]);
                cacc[4*v+2] = fmaf(xr, fb.z, cacc[4*v+2]);
                cacc[4*v+3] = fmaf(xr, fb.w, cacc[4*v+3]);
            }
        }
        float4* an4 = (float4*)(an + (size_t)i * CNXT + g * CPGN);
        float4* cn4 = (float4*)(cn + (size_t)i * CNXT + g * CPGN);
#pragma unroll
        for (int v = 0; v < CPGN / 4; ++v) {
            an4[v] = make_float4(aacc[4*v], aacc[4*v+1], aacc[4*v+2], aacc[4*v+3]);
            cn4[v] = make_float4(cacc[4*v], cacc[4*v+1], cacc[4*v+2], cacc[4*v+3]);
        }
    }
}

// ---------------------------------------------------------------------------
// Workspace layout (bytes), total 33 MB:
//   [0,24M)   : surv (32768 x 192 int, segmented 8x24)  -- dead after P3
//   [24M,25M) : pb  (32768 x 8 float)
//   [25M,+128K): tau
//   [26M,27M) : pc  (32768 x 8 int)
//   [27M,29M) : knn (32768 x 16 int)
//   [29M,31M) : a1 ; [31M,33M) : c1
//   reuse: a2=[0,4M) c2=[4,8M) a3=[8,12M) c3=[12,16M)
// ---------------------------------------------------------------------------
extern "C" void kernel_launch(void* const* d_in, const int* in_sizes, int n_in,
                              void* d_out, int out_size, void* d_ws, size_t ws_size,
                              hipStream_t stream) {
    const float4* coords = (const float4*)d_in[0];
    const float*  feat   = (const float*)d_in[1];
    const float*  W1 = (const float*)d_in[2];
    const float*  b1 = (const float*)d_in[3];
    const float*  W2 = (const float*)d_in[4];
    const float*  b2 = (const float*)d_in[5];
    const float*  W3 = (const float*)d_in[6];
    const float*  b3 = (const float*)d_in[7];
    float* out = (float*)d_out;

    char* ws = (char*)d_ws;
    int*   surv = (int*)  (ws);
    float* pb   = (float*)(ws + (24u << 20));
    float* tau  = (float*)(ws + (25u << 20));
    int*   pc   = (int*)  (ws + (26u << 20));
    int*   knn  = (int*)  (ws + (27u << 20));
    float* a1   = (float*)(ws + (29u << 20));
    float* c1   = (float*)(ws + (31u << 20));
    float* a2   = (float*)(ws + (0u  << 20));
    float* c2   = (float*)(ws + (4u  << 20));
    float* a3   = (float*)(ws + (8u  << 20));
    float* c3   = (float*)(ws + (12u << 20));

    knn_bound_kernel<<<dim3(NPTS / QBLK, CSPLIT), 256, 0, stream>>>(coords, pb);
    tau_init_kernel<<<NPTS / 256, 256, 0, stream>>>(pb, tau);
    knn_filter_kernel<<<dim3(NPTS / QBLK, CSPLIT), 256, 0, stream>>>(coords, tau, pc, surv);
    knn_select_ac1_kernel<<<NPTS, 64, 0, stream>>>(coords, pc, surv, feat, W1, b1, knn, a1, c1);
    edgeconv_kernel<16, 32, false><<<NPTS / 64, 256, 0, stream>>>(a1, c1, knn, W2, b2, a2, c2, nullptr);
    edgeconv_kernel<32, 32, false><<<NPTS / 64, 256, 0, stream>>>(a2, c2, knn, W3, b3, a3, c3, nullptr);
    edgeconv_kernel<32, 4, true><<<NPTS / 64, 256, 0, stream>>>(a3, c3, knn, nullptr, nullptr, nullptr, nullptr, out);
}

// Round 12
// 244.312 us; speedup vs baseline: 7.2412x; 1.2608x over previous
//
#include <hip/hip_runtime.h>
#include <math.h>

#define NPTS 32768
#define NP   8192
#define KNN  16
#define CSPLIT 16
#define CHUNK (NP / CSPLIT)       // 512 candidates per scan chunk
#define SEGCAP 12                 // survivor slots per (query, chunk) segment
#define NSLOT (CSPLIT * SEGCAP)   // 192 slots per query
#define QPT 2                     // queries per thread in scan kernels
#define QBLK (256 * QPT)          // queries per scan block = 512

// Shared distance formula — byte-identical across all phases so float values
// match exactly (bound / filter / select consistency).
__device__ __forceinline__ float dist2f(float qx, float qy, float qz, float sqi, float4 t) {
    float dot = fmaf(qz, t.z, fmaf(qy, t.y, qx * t.x));
    return fmaf(-2.0f, dot, sqi) + t.w;   // reference formula ordering
}

// Branchless: maintain the 16 smallest VALUES seen (sorted ascending).
__device__ __forceinline__ void insert_val(float (&bd)[16], float d) {
    bd[15] = fminf(bd[15], d);
#pragma unroll
    for (int j = 15; j > 0; --j) {
        float lo = fminf(bd[j], bd[j - 1]);
        float hi = fmaxf(bd[j], bd[j - 1]);
        bd[j - 1] = lo; bd[j] = hi;
    }
}

// ---------------------------------------------------------------------------
// P1: bound, QPT=2, 16 chunks. Per (query, chunk): branchless 2-smallest;
// write BOTH (s0,s1). tau = 16th smallest of the 32 collected values — the
// 16 values <= tau are distances of 16 DISTINCT candidates (top-2 of
// disjoint chunks), so tau >= d16 exactly, and is tighter than
// max-of-2nd-smallests (fewer survivors).
// ---------------------------------------------------------------------------
__global__ __launch_bounds__(256) void knn_bound_kernel(
    const float4* __restrict__ coords, float* __restrict__ pb2)
{
    __shared__ float4 tile[CHUNK];   // 8 KB

    const int tid = threadIdx.x;
    const int qb  = blockIdx.x * QBLK;          // 512-query window, no batch straddle
    const int batch = qb / NP;
    const int cbase = batch * NP + blockIdx.y * CHUNK;

    for (int c = tid; c < CHUNK; c += 256) {
        float4 f = coords[cbase + c];                   // [bidx, x, y, z]
        float sq = fmaf(f.w, f.w, fmaf(f.z, f.z, f.y * f.y));
        tile[c] = make_float4(f.y, f.z, f.w, sq);
    }

    const int q0 = qb + tid, q1 = qb + 256 + tid;
    float4 qf0 = coords[q0];
    float4 qf1 = coords[q1];
    const float qx0 = qf0.y, qy0 = qf0.z, qz0 = qf0.w;
    const float qx1 = qf1.y, qy1 = qf1.z, qz1 = qf1.w;
    const float sqi0 = fmaf(qz0, qz0, fmaf(qy0, qy0, qx0 * qx0));
    const float sqi1 = fmaf(qz1, qz1, fmaf(qy1, qy1, qx1 * qx1));

    float a0 = INFINITY, a1 = INFINITY;   // q0: smallest, 2nd-smallest
    float b0 = INFINITY, b1 = INFINITY;   // q1
    __syncthreads();

#pragma unroll 4
    for (int c = 0; c < CHUNK; ++c) {
        float4 t = tile[c];
        float d0 = dist2f(qx0, qy0, qz0, sqi0, t);
        float d1 = dist2f(qx1, qy1, qz1, sqi1, t);
        float t0 = fminf(a1, d0);
        a1 = fmaxf(a0, t0);
        a0 = fminf(a0, t0);
        float t1 = fminf(b1, d1);
        b1 = fmaxf(b0, t1);
        b0 = fminf(b0, t1);
    }
    *(float2*)&pb2[(q0 * CSPLIT + blockIdx.y) * 2] = make_float2(a0, a1);
    *(float2*)&pb2[(q1 * CSPLIT + blockIdx.y) * 2] = make_float2(b0, b1);
}

// ---------------------------------------------------------------------------
// P1.5: tau_q = 16th smallest of the 32 per-chunk top-2 values.
// ---------------------------------------------------------------------------
__global__ __launch_bounds__(256) void tau_init_kernel(
    const float* __restrict__ pb2, float* __restrict__ tau)
{
    const int q = blockIdx.x * 256 + threadIdx.x;
    const float4* row = (const float4*)(pb2 + (size_t)q * 2 * CSPLIT);

    float bd[16];
#pragma unroll
    for (int j = 0; j < 16; ++j) bd[j] = INFINITY;
#pragma unroll
    for (int v = 0; v < 8; ++v) {
        float4 f = row[v];
        insert_val(bd, f.x);
        insert_val(bd, f.y);
        insert_val(bd, f.z);
        insert_val(bd, f.w);
    }
    tau[q] = bd[15];
}

// ---------------------------------------------------------------------------
// P2: filter, QPT=2, ATOMIC-FREE, 16 segments/query. One thread scans each
// (query, chunk) => thread-local counter, fire-and-forget stores. Accept
// path branchless slot clamp; raw count written at end (overflow detect).
// ---------------------------------------------------------------------------
__global__ __launch_bounds__(256) void knn_filter_kernel(
    const float4* __restrict__ coords, const float* __restrict__ tau,
    int* __restrict__ pc, int* __restrict__ surv)
{
    __shared__ float4 tile[CHUNK];

    const int tid = threadIdx.x;
    const int qb  = blockIdx.x * QBLK;
    const int batch = qb / NP;
    const int cbase = batch * NP + blockIdx.y * CHUNK;

    for (int c = tid; c < CHUNK; c += 256) {
        float4 f = coords[cbase + c];
        float sq = fmaf(f.w, f.w, fmaf(f.z, f.z, f.y * f.y));
        tile[c] = make_float4(f.y, f.z, f.w, sq);
    }

    const int q0 = qb + tid, q1 = qb + 256 + tid;
    float4 qf0 = coords[q0];
    float4 qf1 = coords[q1];
    const float qx0 = qf0.y, qy0 = qf0.z, qz0 = qf0.w;
    const float qx1 = qf1.y, qy1 = qf1.z, qz1 = qf1.w;
    const float sqi0 = fmaf(qz0, qz0, fmaf(qy0, qy0, qx0 * qx0));
    const float sqi1 = fmaf(qz1, qz1, fmaf(qy1, qy1, qx1 * qx1));
    const float tq0 = tau[q0], tq1 = tau[q1];

    const size_t sb0 = (size_t)q0 * NSLOT + blockIdx.y * SEGCAP;
    const size_t sb1 = (size_t)q1 * NSLOT + blockIdx.y * SEGCAP;
    int cnt0 = 0, cnt1 = 0;
    __syncthreads();

#pragma unroll 4
    for (int c = 0; c < CHUNK; ++c) {
        float4 t = tile[c];
        float d0 = dist2f(qx0, qy0, qz0, sqi0, t);
        float d1 = dist2f(qx1, qy1, qz1, sqi1, t);
        if (d0 <= tq0) {
            surv[sb0 + (cnt0 < SEGCAP ? cnt0 : SEGCAP - 1)] = cbase + c;
            ++cnt0;
        }
        if (d1 <= tq1) {
            surv[sb1 + (cnt1 < SEGCAP ? cnt1 : SEGCAP - 1)] = cbase + c;
            ++cnt1;
        }
    }
    pc[q0 * CSPLIT + blockIdx.y] = cnt0;
    pc[q1 * CSPLIT + blockIdx.y] = cnt1;
}

// ---------------------------------------------------------------------------
// P3: WAVE-PARALLEL exact top-16 + layer-1 a1/c1, compacted rank.
// One wave per query. Survivors compacted into LDS via prefix offsets (LDS,
// avoids runtime-indexed register array spill). Rank loop runs k < n (~30
// avg). Lex (d,id) strict total order -> bijective ranks, exact jax
// tie-break. Overflow (P~1e-7) -> WAVE-PARALLEL 16-round extraction (no
// serial 300us tail). Single-wave block => uniform-control __syncthreads.
// ---------------------------------------------------------------------------
__global__ __launch_bounds__(64) void knn_select_ac1_kernel(
    const float4* __restrict__ coords, const int* __restrict__ pc,
    const int* __restrict__ surv,
    const float* __restrict__ feat, const float* __restrict__ W1,
    const float* __restrict__ b1,
    int* __restrict__ knn, float* __restrict__ a1, float* __restrict__ c1)
{
    __shared__ float sd[NSLOT];
    __shared__ int   si[NSLOT];
    __shared__ int   spc[CSPLIT];
    __shared__ int   soff[CSPLIT];
    __shared__ int   outi[16];
    __shared__ float sx[16];

    const int lane = threadIdx.x;
    const int q    = blockIdx.x;

    float4 qf = coords[q];
    const float qx = qf.y, qy = qf.z, qz = qf.w;
    const float sqi = fmaf(qz, qz, fmaf(qy, qy, qx * qx));

    if (lane < CSPLIT) spc[lane] = pc[q * CSPLIT + lane];
    __syncthreads();

    // Wave-uniform scalars: overflow flag + total n; prefix offsets -> LDS.
    bool over = false;
    int acc = 0;
#pragma unroll
    for (int s = 0; s < CSPLIT; ++s) {
        int c = spc[s];
        over |= (c > SEGCAP);
        if (lane == 0) soff[s] = acc;
        acc += c;
    }
    const int n = acc;                        // >= 16 by construction when !over
    __syncthreads();

    if (!over) {
        // Compacted stage: slot j -> LDS position soff[seg]+o (injective).
#pragma unroll
        for (int b = 0; b < 3; ++b) {
            const int j = b * 64 + lane;      // j < 192
            const int seg = j / SEGCAP;
            const int o   = j - seg * SEGCAP;
            if (o < spc[seg]) {
                int id = surv[(size_t)q * NSLOT + j];
                float4 f = coords[id];
                float sq = fmaf(f.w, f.w, fmaf(f.z, f.z, f.y * f.y));
                float d = dist2f(qx, qy, qz, sqi, make_float4(f.y, f.z, f.w, sq));
                const int pos = soff[seg] + o;
                sd[pos] = d; si[pos] = id;
            }
        }
        __syncthreads();

        if (n <= 64) {                        // dominant path (n ~ 25-40)
            float dm = INFINITY; int im = 0x7fffffff;
            if (lane < n) { dm = sd[lane]; im = si[lane]; }
            int r = 0;
            for (int k = 0; k < n; ++k) {     // LDS broadcast reads
                float dk = sd[k]; int ik = si[k];
                r += ((dk < dm) || (dk == dm && ik < im)) ? 1 : 0;
            }
            if (lane < n && r < 16) outi[r] = im;
        } else {
            float dm[3]; int im[3];
#pragma unroll
            for (int b = 0; b < 3; ++b) {
                const int m = b * 64 + lane;
                dm[b] = (m < n) ? sd[m] : INFINITY;
                im[b] = (m < n) ? si[m] : 0x7fffffff;
            }
            int r0 = 0, r1 = 0, r2 = 0;
            for (int k = 0; k < n; ++k) {
                float dk = sd[k]; int ik = si[k];
                r0 += ((dk < dm[0]) || (dk == dm[0] && ik < im[0])) ? 1 : 0;
                r1 += ((dk < dm[1]) || (dk == dm[1] && ik < im[1])) ? 1 : 0;
                r2 += ((dk < dm[2]) || (dk == dm[2] && ik < im[2])) ? 1 : 0;
            }
            if (lane       < n && r0 < 16) outi[r0] = im[0];
            if (lane + 64  < n && r1 < 16) outi[r1] = im[1];
            if (lane + 128 < n && r2 < 16) outi[r2] = im[2];
        }
        __syncthreads();
    } else {
        // WAVE-PARALLEL exact fallback: 16 extraction rounds. Each round,
        // every lane scans its 128-candidate stride for the lex-min strictly
        // greater than the last extracted; butterfly lex-min across lanes.
        const int b0 = (q / NP) * NP;
        float lastd = -INFINITY; int lasti = -1;
        for (int r = 0; r < 16; ++r) {
            float md = INFINITY; int mi = 0x7fffffff;
            for (int c = lane; c < NP; c += 64) {
                int id = b0 + c;
                float4 f = coords[id];
                float sq = fmaf(f.w, f.w, fmaf(f.z, f.z, f.y * f.y));
                float d = dist2f(qx, qy, qz, sqi, make_float4(f.y, f.z, f.w, sq));
                bool gt_last = (d > lastd) || (d == lastd && id > lasti);
                bool lt_min  = (d < md) || (d == md && id < mi);
                if (gt_last && lt_min) { md = d; mi = id; }
            }
#pragma unroll
            for (int s = 1; s < 64; s <<= 1) {     // lex-min butterfly
                float od = __shfl_xor(md, s);
                int   oi = __shfl_xor(mi, s);
                bool less = (od < md) || (od == md && oi < mi);
                md = less ? od : md;
                mi = less ? oi : mi;
            }
            if (lane == 0) outi[r] = mi;
            lastd = md; lasti = mi;                // uniform after butterfly
        }
        __syncthreads();
    }

    if (lane < 16) {
        knn[q * 16 + lane] = outi[lane];
        sx[lane] = feat[(size_t)q * 16 + lane];
    }
    __syncthreads();

    // ---- a1/c1: lane c (<16) computes channel c ----
    if (lane < 16) {
        float av = b1[lane], cv = 0.0f;
#pragma unroll
        for (int r = 0; r < 16; ++r) {
            float xr = sx[r];
            float wt = W1[r * 16 + lane];
            float wb = W1[(16 + r) * 16 + lane];
            av = fmaf(xr, wt - wb, av);
            cv = fmaf(xr, wb, cv);
        }
        a1[(size_t)q * 16 + lane] = av;
        c1[(size_t)q * 16 + lane] = cv;
    }
}

// ---------------------------------------------------------------------------
// EdgeConv (unchanged, passing since round 0):
//   x_out[i] = relu( max_k (a[i] + c[knn[i][k]]) )
// ---------------------------------------------------------------------------
template<int COUT, int CNXT, bool LAST>
__global__ __launch_bounds__(256) void edgeconv_kernel(
    const float* __restrict__ a, const float* __restrict__ cf,
    const int* __restrict__ knn,
    const float* __restrict__ Wn, const float* __restrict__ bn,
    float* __restrict__ an, float* __restrict__ cn, float* __restrict__ out)
{
    constexpr int CPG  = COUT / 4;
    constexpr int CPGN = LAST ? 4 : CNXT / 4;
    constexpr int WSZ  = LAST ? 1 : COUT * CNXT;

    __shared__ float xs[64][COUT + 1];
    __shared__ __align__(16) float wm[WSZ];
    __shared__ __align__(16) float wb[WSZ];

    const int tid = threadIdx.x;
    const int g = tid & 3, p = tid >> 2;
    const int i = blockIdx.x * 64 + p;

    if constexpr (!LAST) {
        for (int t = tid; t < COUT * CNXT; t += 256) {
            float top = Wn[t], bot = Wn[COUT * CNXT + t];
            wm[t] = top - bot; wb[t] = bot;
        }
    }

    float av[CPG], m[CPG];
    const float4* a4 = (const float4*)(a + (size_t)i * COUT + g * CPG);
#pragma unroll
    for (int v = 0; v < CPG / 4; ++v) {
        float4 f = a4[v];
        av[4*v] = f.x; av[4*v+1] = f.y; av[4*v+2] = f.z; av[4*v+3] = f.w;
    }
#pragma unroll
    for (int c = 0; c < CPG; ++c) m[c] = -INFINITY;

    const int4* kn = (const int4*)(knn + (size_t)i * 16);
#pragma unroll
    for (int kk = 0; kk < 4; ++kk) {
        int4 n4 = kn[kk];
        int js[4] = { n4.x, n4.y, n4.z, n4.w };
#pragma unroll
        for (int u = 0; u < 4; ++u) {
            const float4* c4 = (const float4*)(cf + (size_t)js[u] * COUT + g * CPG);
#pragma unroll
            for (int v = 0; v < CPG / 4; ++v) {
                float4 f = c4[v];
                m[4*v+0] = fmaxf(m[4*v+0], av[4*v+0] + f.x);
                m[4*v+1] = fmaxf(m[4*v+1], av[4*v+1] + f.y);
                m[4*v+2] = fmaxf(m[4*v+2], av[4*v+2] + f.z);
                m[4*v+3] = fmaxf(m[4*v+3], av[4*v+3] + f.w);
            }
        }
    }
    float xv[CPG];
#pragma unroll
    for (int c = 0; c < CPG; ++c) xv[c] = fmaxf(m[c], 0.0f);

    if constexpr (LAST) {
        float4* o4 = (float4*)(out + (size_t)i * COUT + g * CPG);
#pragma unroll
        for (int v = 0; v < CPG / 4; ++v)
            o4[v] = make_float4(xv[4*v], xv[4*v+1], xv[4*v+2], xv[4*v+3]);
    } else {
#pragma unroll
        for (int c = 0; c < CPG; ++c) xs[p][g * CPG + c] = xv[c];
        __syncthreads();

        float aacc[CPGN], cacc[CPGN];
        const float4* bn4 = (const float4*)(bn + g * CPGN);
#pragma unroll
        for (int v = 0; v < CPGN / 4; ++v) {
            float4 f = bn4[v];
            aacc[4*v] = f.x; aacc[4*v+1] = f.y; aacc[4*v+2] = f.z; aacc[4*v+3] = f.w;
        }
#pragma unroll
        for (int c = 0; c < CPGN; ++c) cacc[c] = 0.0f;

#pragma unroll
        for (int r = 0; r < COUT; ++r) {
            float xr = xs[p][r];
            const float4* wm4 = (const float4*)(wm + r * CNXT + g * CPGN);
            const float4* wb4 = (const float4*)(wb + r * CNXT + g * CPGN);
#pragma unroll
            for (int v = 0; v < CPGN / 4; ++v) {
                float4 fm = wm4[v], fb = wb4[v];
                aacc[4*v+0] = fmaf(xr, fm.x, aacc[4*v+0]);
                aacc[4*v+1] = fmaf(xr, fm.y, aacc[4*v+1]);
                aacc[4*v+2] = fmaf(xr, fm.z, aacc[4*v+2]);
                aacc[4*v+3] = fmaf(xr, fm.w, aacc[4*v+3]);
                cacc[4*v+0] = fmaf(xr, fb.x, cacc[4*v+0]);
                cacc[4*v+1] = fmaf(xr, fb.y, cacc[4*v+1]);
                cacc[4*v+2] = fmaf(xr, fb.z, cacc[4*v+2]);
                cacc[4*v+3] = fmaf(xr, fb.w, cacc[4*v+3]);
            }
        }
        float4* an4 = (float4*)(an + (size_t)i * CNXT + g * CPGN);
        float4* cn4 = (float4*)(cn + (size_t)i * CNXT + g * CPGN);
#pragma unroll
        for (int v = 0; v < CPGN / 4; ++v) {
            an4[v] = make_float4(aacc[4*v], aacc[4*v+1], aacc[4*v+2], aacc[4*v+3]);
            cn4[v] = make_float4(cacc[4*v], cacc[4*v+1], cacc[4*v+2], cacc[4*v+3]);
        }
    }
}

// ---------------------------------------------------------------------------
// Workspace layout (bytes), total 37 MB (<= proven 38 MB budget):
//   [0,24M)   : surv (32768 x 192 int, segmented 16x12)  -- dead after P3
//   [24M,28M) : pb2 (32768 x 16 chunks x 2 floats)
//   [28M,+128K): tau
//   [29M,31M) : pc  (32768 x 16 int)
//   [31M,33M) : knn (32768 x 16 int)
//   [33M,35M) : a1 ; [35M,37M) : c1
//   reuse: a2=[0,4M) c2=[4,8M) a3=[8,12M) c3=[12,16M)
// ---------------------------------------------------------------------------
extern "C" void kernel_launch(void* const* d_in, const int* in_sizes, int n_in,
                              void* d_out, int out_size, void* d_ws, size_t ws_size,
                              hipStream_t stream) {
    const float4* coords = (const float4*)d_in[0];
    const float*  feat   = (const float*)d_in[1];
    const float*  W1 = (const float*)d_in[2];
    const float*  b1 = (const float*)d_in[3];
    const float*  W2 = (const float*)d_in[4];
    const float*  b2 = (const float*)d_in[5];
    const float*  W3 = (const float*)d_in[6];
    const float*  b3 = (const float*)d_in[7];
    float* out = (float*)d_out;

    char* ws = (char*)d_ws;
    int*   surv = (int*)  (ws);
    float* pb2  = (float*)(ws + (24u << 20));
    float* tau  = (float*)(ws + (28u << 20));
    int*   pc   = (int*)  (ws + (29u << 20));
    int*   knn  = (int*)  (ws + (31u << 20));
    float* a1   = (float*)(ws + (33u << 20));
    float* c1   = (float*)(ws + (35u << 20));
    float* a2   = (float*)(ws + (0u  << 20));
    float* c2   = (float*)(ws + (4u  << 20));
    float* a3   = (float*)(ws + (8u  << 20));
    float* c3   = (float*)(ws + (12u << 20));

    knn_bound_kernel<<<dim3(NPTS / QBLK, CSPLIT), 256, 0, stream>>>(coords, pb2);
    tau_init_kernel<<<NPTS / 256, 256, 0, stream>>>(pb2, tau);
    knn_filter_kernel<<<dim3(NPTS / QBLK, CSPLIT), 256, 0, stream>>>(coords, tau, pc, surv);
    knn_select_ac1_kernel<<<NPTS, 64, 0, stream>>>(coords, pc, surv, feat, W1, b1, knn, a1, c1);
    edgeconv_kernel<16, 32, false><<<NPTS / 64, 256, 0, stream>>>(a1, c1, knn, W2, b2, a2, c2, nullptr);
    edgeconv_kernel<32, 32, false><<<NPTS / 64, 256, 0, stream>>>(a2, c2, knn, W3, b3, a3, c3, nullptr);
    edgeconv_kernel<32, 4, true><<<NPTS / 64, 256, 0, stream>>>(a3, c3, knn, nullptr, nullptr, nullptr, nullptr, out);
}